// Round 2
// baseline (702.659 us; speedup 1.0000x reference)
//
#include <hip/hip_runtime.h>
#include <hip/hip_bf16.h>
#include <stdint.h>

#define BB 2
#define LL 2048
#define KNN 48
#define MAXREL 32
#define EDGE_D 128
#define EIN 416        // 16 positional + 5*5*16 RBF
#define ROWS 24        // edges per workgroup (half of KNN)

__device__ __forceinline__ unsigned long long u64min(unsigned long long a, unsigned long long b) {
    return a < b ? a : b;
}

__device__ __forceinline__ unsigned long long shfl_xor_u64(unsigned long long v, int m) {
    unsigned lo = __shfl_xor((unsigned)(v & 0xffffffffull), m);
    unsigned hi = __shfl_xor((unsigned)(v >> 32), m);
    return (((unsigned long long)hi) << 32) | lo;
}

// ---------------------------------------------------------------------------
// Kernel 1: exact kNN (top-48 smallest adjusted Ca-Ca distances per residue).
// Key = (f32 bits of D_adjust) << 32 | j  -> ascending u64 order == jax.lax.top_k
// (stable: ties broken by lower index). One 256-thread WG per (b,i); 8 keys
// per thread in registers; 48 serial min-reductions with removal.
// wmin double-buffered -> ONE barrier per selection iteration (WAR removed).
// Distances use non-contracted fp32 ops to match XLA rounding.
// ---------------------------------------------------------------------------
__global__ __launch_bounds__(256) void knn_kernel(
    const float* __restrict__ X, const float* __restrict__ mask,
    int* __restrict__ eidx_i, float* __restrict__ eidx_f)
{
    const int bi  = blockIdx.x;
    const int b   = bi >> 11;      // / 2048
    const int i   = bi & (LL - 1);
    const int tid = threadIdx.x;

    const float* Xb = X + (size_t)b * LL * 12;
    const float* mb = mask + (size_t)b * LL;

    const float cax = Xb[i * 12 + 3];
    const float cay = Xb[i * 12 + 4];
    const float caz = Xb[i * 12 + 5];
    const float mi  = mb[i];

    float D[8], M2[8];
    float dmax = 0.0f;

    #pragma unroll
    for (int t = 0; t < 8; t++) {
        int j = tid + (t << 8);
        float dx = Xb[j * 12 + 3] - cax;
        float dy = Xb[j * 12 + 4] - cay;
        float dz = Xb[j * 12 + 5] - caz;
        float s  = __fadd_rn(__fadd_rn(__fmul_rn(dx, dx), __fmul_rn(dy, dy)),
                             __fmul_rn(dz, dz));
        float m2 = __fmul_rn(mi, mb[j]);
        float d  = __fmul_rn(m2, sqrtf(__fadd_rn(s, 1e-6f)));
        D[t]  = d;
        M2[t] = m2;
        dmax  = fmaxf(dmax, d);
    }

    __shared__ float wsh[4];
    __shared__ unsigned long long wmin[2][4];   // double-buffered per iteration

    // row max of D (for the masked adjustment)
    #pragma unroll
    for (int off = 32; off; off >>= 1) dmax = fmaxf(dmax, __shfl_xor(dmax, off));
    if ((tid & 63) == 0) wsh[tid >> 6] = dmax;
    __syncthreads();
    dmax = fmaxf(fmaxf(wsh[0], wsh[1]), fmaxf(wsh[2], wsh[3]));

    unsigned long long key[8];
    #pragma unroll
    for (int t = 0; t < 8; t++) {
        float dadj = __fadd_rn(D[t], __fmul_rn(1.0f - M2[t], dmax));
        key[t] = (((unsigned long long)__float_as_uint(dadj)) << 32)
               | (unsigned)(tid + (t << 8));
    }

    for (int s = 0; s < KNN; s++) {
        unsigned long long lmin = key[0];
        #pragma unroll
        for (int t = 1; t < 8; t++) lmin = u64min(lmin, key[t]);
        #pragma unroll
        for (int off = 32; off; off >>= 1) lmin = u64min(lmin, shfl_xor_u64(lmin, off));
        if ((tid & 63) == 0) wmin[s & 1][tid >> 6] = lmin;
        __syncthreads();
        unsigned long long gmin =
            u64min(u64min(wmin[s & 1][0], wmin[s & 1][1]),
                   u64min(wmin[s & 1][2], wmin[s & 1][3]));
        if (tid == 0) {
            int j = (int)(gmin & 0xffffffffu);
            eidx_i[(size_t)bi * KNN + s] = j;
            eidx_f[(size_t)bi * KNN + s] = (float)j;
        }
        #pragma unroll
        for (int t = 0; t < 8; t++) if (key[t] == gmin) key[t] = ~0ull;
        // no second barrier: next iteration writes the OTHER wmin buffer
    }
}

// ---------------------------------------------------------------------------
// Kernel 2: edge features (positional one-hot@W_pos + 25x16 RBF) -> 416x128
// projection -> LayerNorm -> E. One 256-thread WG per (b, i, half): 24 edges.
// GEMM: thread = (col c, row-group g); per 4 k-steps: 4 coalesced W loads +
// 12 broadcast ds_read_b128 of the LDS feature tile + 48 fp32 fma.
// ---------------------------------------------------------------------------
__global__ __launch_bounds__(256) void edge_kernel(
    const float* __restrict__ X,
    const int*   __restrict__ ridx, const int* __restrict__ chain,
    const float* __restrict__ Wpos, const float* __restrict__ bpos,
    const float* __restrict__ Wedge,
    const float* __restrict__ gamma, const float* __restrict__ beta,
    const int*   __restrict__ eidx_i, float* __restrict__ Eout)
{
    __shared__ float feat[ROWS][420];        // 416 + pad
    __shared__ float nbat[ROWS][5][3];       // neighbor atoms: Ca,N,C,O,Cb
    __shared__ float ctr[5][3];              // center atoms
    __shared__ int   nbi[ROWS];
    __shared__ int   dsel[ROWS];
    __shared__ float mrow[ROWS];
    __shared__ float rrow[ROWS];

    const int wg  = blockIdx.x;
    const int h   = wg & 1;
    const int bi  = wg >> 1;
    const int b   = bi >> 11;
    const int i   = bi & (LL - 1);
    const int tid = threadIdx.x;
    const float* Xb = X + (size_t)b * LL * 12;

    if (tid < ROWS) {
        int j = eidx_i[(size_t)bi * KNN + h * ROWS + tid];
        nbi[tid] = j;
        int off = ridx[b * LL + i] - ridx[b * LL + j];
        int sc  = (chain[b * LL + i] == chain[b * LL + j]);
        int dcl = off + MAXREL;
        dcl = dcl < 0 ? 0 : (dcl > 2 * MAXREL ? 2 * MAXREL : dcl);
        dsel[tid] = sc ? dcl : (2 * MAXREL + 1);
    }
    __syncthreads();

    // atom order in features: 0=Ca(X slot1), 1=N(slot0), 2=C(slot2), 3=O(slot3)
    if (tid < 96) {
        int e = tid >> 2, a = tid & 3;
        int src = (a == 0) ? 1 : ((a == 1) ? 0 : a);
        int j = nbi[e];
        nbat[e][a][0] = Xb[j * 12 + src * 3 + 0];
        nbat[e][a][1] = Xb[j * 12 + src * 3 + 1];
        nbat[e][a][2] = Xb[j * 12 + src * 3 + 2];
    } else if (tid < 100) {
        int a = tid - 96;
        int src = (a == 0) ? 1 : ((a == 1) ? 0 : a);
        ctr[a][0] = Xb[i * 12 + src * 3 + 0];
        ctr[a][1] = Xb[i * 12 + src * 3 + 1];
        ctr[a][2] = Xb[i * 12 + src * 3 + 2];
    }
    __syncthreads();

    // virtual Cb = -0.58273431*a + 0.56802827*b - 0.54067466*c + Ca
    // with b = Ca-N, c = C-Ca, a = b x c
    if (tid < ROWS) {
        float bx = nbat[tid][0][0] - nbat[tid][1][0];
        float by = nbat[tid][0][1] - nbat[tid][1][1];
        float bz = nbat[tid][0][2] - nbat[tid][1][2];
        float cx = nbat[tid][2][0] - nbat[tid][0][0];
        float cy = nbat[tid][2][1] - nbat[tid][0][1];
        float cz = nbat[tid][2][2] - nbat[tid][0][2];
        float ax = by * cz - bz * cy;
        float ay = bz * cx - bx * cz;
        float az = bx * cy - by * cx;
        nbat[tid][4][0] = -0.58273431f * ax + 0.56802827f * bx - 0.54067466f * cx + nbat[tid][0][0];
        nbat[tid][4][1] = -0.58273431f * ay + 0.56802827f * by - 0.54067466f * cy + nbat[tid][0][1];
        nbat[tid][4][2] = -0.58273431f * az + 0.56802827f * bz - 0.54067466f * cz + nbat[tid][0][2];
    } else if (tid == 32) {
        float bx = ctr[0][0] - ctr[1][0];
        float by = ctr[0][1] - ctr[1][1];
        float bz = ctr[0][2] - ctr[1][2];
        float cx = ctr[2][0] - ctr[0][0];
        float cy = ctr[2][1] - ctr[0][1];
        float cz = ctr[2][2] - ctr[0][2];
        float ax = by * cz - bz * cy;
        float ay = bz * cx - bx * cz;
        float az = bx * cy - by * cx;
        ctr[4][0] = -0.58273431f * ax + 0.56802827f * bx - 0.54067466f * cx + ctr[0][0];
        ctr[4][1] = -0.58273431f * ay + 0.56802827f * by - 0.54067466f * cy + ctr[0][1];
        ctr[4][2] = -0.58273431f * az + 0.56802827f * bz - 0.54067466f * cz + ctr[0][2];
    }
    __syncthreads();

    // positional features: one-hot(dsel) @ W_pos + b_pos  ==  W_pos[dsel] + b_pos
    for (int idx = tid; idx < ROWS * 16; idx += 256) {
        int e = idx >> 4, p = idx & 15;
        feat[e][p] = Wpos[dsel[e] * 16 + p] + bpos[p];
    }
    // RBF features: center atom A vs neighbor atom Bv
    for (int idx = tid; idx < ROWS * 25; idx += 256) {
        int e = idx / 25, pr = idx % 25;
        int A = pr / 5, Bv = pr % 5;
        float dx = ctr[A][0] - nbat[e][Bv][0];
        float dy = ctr[A][1] - nbat[e][Bv][1];
        float dz = ctr[A][2] - nbat[e][Bv][2];
        float d  = sqrtf(dx * dx + dy * dy + dz * dz + 1e-6f);
        float* f = &feat[e][16 + pr * 16];
        #pragma unroll
        for (int r = 0; r < 16; r++) {
            float mu = 2.0f + 1.3333334f * (float)r;   // linspace(2,22,16)
            float tq = (d - mu) * 0.8f;                // / sigma=1.25
            f[r] = __expf(-tq * tq);
        }
    }
    __syncthreads();

    // GEMM: 24x416 (LDS) @ 416x128 (global, coalesced) -> acc[12] per thread
    const int c = tid & 127;
    const int g = tid >> 7;
    const float* wp = Wedge + c;
    float acc[12];
    #pragma unroll
    for (int rr = 0; rr < 12; rr++) acc[rr] = 0.0f;

    for (int t = 0; t < EIN; t += 4) {
        float w0 = wp[(size_t)(t + 0) * EDGE_D];
        float w1 = wp[(size_t)(t + 1) * EDGE_D];
        float w2 = wp[(size_t)(t + 2) * EDGE_D];
        float w3 = wp[(size_t)(t + 3) * EDGE_D];
        #pragma unroll
        for (int rr = 0; rr < 12; rr++) {
            float4 f = *(const float4*)(&feat[g * 12 + rr][t]);
            acc[rr] += f.x * w0 + f.y * w1 + f.z * w2 + f.w * w3;
        }
    }
    __syncthreads();

    // LayerNorm over the 128 outputs of each edge row
    float (*Et)[132] = reinterpret_cast<float(*)[132]>(&feat[0][0]);
    #pragma unroll
    for (int rr = 0; rr < 12; rr++) Et[g * 12 + rr][c] = acc[rr];
    __syncthreads();

    if (tid < 192) {
        int r = tid >> 3, l = tid & 7;
        float s = 0.0f;
        for (int q = l; q < 128; q += 8) s += Et[r][q];
        s += __shfl_xor(s, 1); s += __shfl_xor(s, 2); s += __shfl_xor(s, 4);
        if (l == 0) mrow[r] = s * 0.0078125f;
    }
    __syncthreads();
    if (tid < 192) {
        int r = tid >> 3, l = tid & 7;
        float m = mrow[r], s = 0.0f;
        for (int q = l; q < 128; q += 8) { float df = Et[r][q] - m; s += df * df; }
        s += __shfl_xor(s, 1); s += __shfl_xor(s, 2); s += __shfl_xor(s, 4);
        if (l == 0) rrow[r] = rsqrtf(s * 0.0078125f + 1e-5f);
    }
    __syncthreads();

    float* Eo = Eout + ((size_t)bi * KNN + h * ROWS) * EDGE_D;
    const float gm = gamma[c], bt = beta[c];
    #pragma unroll
    for (int rr = 0; rr < 12; rr++) {
        int r = g * 12 + rr;
        Eo[(size_t)r * EDGE_D + c] = (acc[rr] - mrow[r]) * rrow[r] * gm + bt;
    }
}

extern "C" void kernel_launch(void* const* d_in, const int* in_sizes, int n_in,
                              void* d_out, int out_size, void* d_ws, size_t ws_size,
                              hipStream_t stream) {
    const float* X     = (const float*)d_in[0];
    const float* mask  = (const float*)d_in[1];
    const int*   ridx  = (const int*)d_in[2];
    const int*   chain = (const int*)d_in[3];
    const float* Wpos  = (const float*)d_in[4];
    const float* bpos  = (const float*)d_in[5];
    const float* Wedge = (const float*)d_in[6];
    const float* gamma = (const float*)d_in[7];
    const float* beta  = (const float*)d_in[8];

    float* out     = (float*)d_out;
    float* Eout    = out;                                   // B*L*K*128 floats
    float* eidx_f  = out + (size_t)BB * LL * KNN * EDGE_D;  // B*L*K floats
    int*   eidx_i  = (int*)d_ws;                            // B*L*K ints

    hipLaunchKernelGGL(knn_kernel, dim3(BB * LL), dim3(256), 0, stream,
                       X, mask, eidx_i, eidx_f);
    hipLaunchKernelGGL(edge_kernel, dim3(BB * LL * 2), dim3(256), 0, stream,
                       X, ridx, chain, Wpos, bpos, Wedge, gamma, beta, eidx_i, Eout);
}

// Round 3
// 360.651 us; speedup vs baseline: 1.9483x; 1.9483x over previous
//
#include <hip/hip_runtime.h>
#include <hip/hip_bf16.h>
#include <stdint.h>

#define BB 2
#define LL 2048
#define KNN 48
#define MAXREL 32
#define EDGE_D 128
#define FSTRIDE 232            // ushorts per feature row (chunk-local K max 224, +pad)
#define FLOFF   11136          // 48*FSTRIDE: element offset of the "lo" plane in fHL
#define WFH_ELEMS 53248        // 13*8*64*8: one plane of W fragments
#define EIDX_BYTES (BB*LL*KNN*4)

typedef unsigned long long u64;
typedef __bf16 bf16_t;
typedef bf16_t bf16x8 __attribute__((ext_vector_type(8)));
typedef float f32x4 __attribute__((ext_vector_type(4)));

union U16x8 { uint4 q; bf16x8 v; };

__device__ __forceinline__ u64 u64min(u64 a, u64 b) { return a < b ? a : b; }

__device__ __forceinline__ u64 shfl_xor_u64(u64 v, int m) {
    unsigned lo = __shfl_xor((unsigned)(v & 0xffffffffull), m);
    unsigned hi = __shfl_xor((unsigned)(v >> 32), m);
    return (((u64)hi) << 32) | lo;
}

// truncation split: f = hi + lo + eps, |eps| ~ 2^-16 |f|
__device__ __forceinline__ void split_hi_lo(float f, unsigned short& h, unsigned short& l) {
    unsigned bits = __float_as_uint(f);
    h = (unsigned short)(bits >> 16);
    float hf = __uint_as_float(bits & 0xffff0000u);
    float lo = f - hf;
    l = (unsigned short)(__float_as_uint(lo) >> 16);
}

// ---------------------------------------------------------------------------
// Kernel 0: split W_edge (416x128 f32) into bf16 hi/lo planes, pre-swizzled
// into mfma_f32_16x16x32_bf16 B-fragment order:
//   elem((ktg,nt,lane,e)) = ((ktg*8+nt)*64+lane)*8+e ;  B[k][n],
//   k = ktg*32 + (lane>>4)*8 + e, n = nt*16 + (lane&15).
// ---------------------------------------------------------------------------
__global__ __launch_bounds__(256) void prep_kernel(const float* __restrict__ W,
                                                   unsigned short* __restrict__ Wf)
{
    int tid = blockIdx.x * 256 + threadIdx.x;
    if (tid >= WFH_ELEMS) return;
    int e    = tid & 7;
    int lane = (tid >> 3) & 63;
    int nt   = (tid >> 9) & 7;
    int ktg  = tid >> 12;
    int k    = ktg * 32 + ((lane >> 4) << 3) + e;
    int col  = (nt << 4) + (lane & 15);
    float f  = W[k * 128 + col];
    unsigned short h, l;
    split_hi_lo(f, h, l);
    Wf[tid]             = h;
    Wf[tid + WFH_ELEMS] = l;
}

// ---------------------------------------------------------------------------
// Kernel 1: exact kNN. u64 key = (f32 bits of D_adjust)<<32 | j  (ascending ==
// jax.lax.top_k order incl. tie-break). Phase A: each of 4 waves selects its
// top-48 of its 512 candidates (no barriers, wave ops only). Phase B: wave 0
// extract-mins the 192 survivors. 2 barriers total (was 96).
// ---------------------------------------------------------------------------
__global__ __launch_bounds__(256) void knn_kernel(
    const float* __restrict__ X, const float* __restrict__ mask,
    int* __restrict__ eidx_i, float* __restrict__ eidx_f)
{
    const int bi   = blockIdx.x;
    const int b    = bi >> 11;
    const int i    = bi & (LL - 1);
    const int tid  = threadIdx.x;
    const int wv   = tid >> 6;
    const int lane = tid & 63;

    const float* Xb = X + (size_t)b * LL * 12;
    const float* mb = mask + (size_t)b * LL;

    const float cax = Xb[i * 12 + 3];
    const float cay = Xb[i * 12 + 4];
    const float caz = Xb[i * 12 + 5];
    const float mi  = mb[i];

    float D[8], M2[8];
    float dmax = 0.0f;

    #pragma unroll
    for (int t = 0; t < 8; t++) {
        int j = (wv << 9) + (t << 6) + lane;
        float dx = Xb[j * 12 + 3] - cax;
        float dy = Xb[j * 12 + 4] - cay;
        float dz = Xb[j * 12 + 5] - caz;
        float s  = __fadd_rn(__fadd_rn(__fmul_rn(dx, dx), __fmul_rn(dy, dy)),
                             __fmul_rn(dz, dz));
        float m2 = __fmul_rn(mi, mb[j]);
        float d  = __fmul_rn(m2, sqrtf(__fadd_rn(s, 1e-6f)));
        D[t]  = d;
        M2[t] = m2;
        dmax  = fmaxf(dmax, d);
    }

    __shared__ float wsh[4];
    __shared__ u64 lists[4][KNN];

    #pragma unroll
    for (int off = 32; off; off >>= 1) dmax = fmaxf(dmax, __shfl_xor(dmax, off));
    if (lane == 0) wsh[wv] = dmax;
    __syncthreads();
    dmax = fmaxf(fmaxf(wsh[0], wsh[1]), fmaxf(wsh[2], wsh[3]));

    u64 key[8];
    #pragma unroll
    for (int t = 0; t < 8; t++) {
        int j = (wv << 9) + (t << 6) + lane;
        float dadj = __fadd_rn(D[t], __fmul_rn(1.0f - M2[t], dmax));
        key[t] = (((u64)__float_as_uint(dadj)) << 32) | (unsigned)j;
    }

    // Phase A: wave-local top-48 (sorted), no WG barriers.
    for (int s = 0; s < KNN; s++) {
        u64 m = key[0];
        #pragma unroll
        for (int t = 1; t < 8; t++) m = u64min(m, key[t]);
        #pragma unroll
        for (int off = 1; off < 64; off <<= 1) m = u64min(m, shfl_xor_u64(m, off));
        if (lane == 0) lists[wv][s] = m;
        #pragma unroll
        for (int t = 0; t < 8; t++) if (key[t] == m) key[t] = ~0ull;
    }
    __syncthreads();

    // Phase B: wave 0 merges 4x48 (3 keys/lane), emitting in global sorted order.
    if (wv == 0) {
        const u64* Lf = &lists[0][0];
        u64 k0 = Lf[lane], k1 = Lf[lane + 64], k2 = Lf[lane + 128];
        for (int s = 0; s < KNN; s++) {
            u64 m = u64min(k0, u64min(k1, k2));
            #pragma unroll
            for (int off = 1; off < 64; off <<= 1) m = u64min(m, shfl_xor_u64(m, off));
            if (lane == 0) {
                int j = (int)(m & 0xffffffffu);
                eidx_i[(size_t)bi * KNN + s] = j;
                eidx_f[(size_t)bi * KNN + s] = (float)j;
            }
            k0 = (k0 == m) ? ~0ull : k0;
            k1 = (k1 == m) ? ~0ull : k1;
            k2 = (k2 == m) ? ~0ull : k2;
        }
    }
}

// ---------------------------------------------------------------------------
// Kernel 2: features -> split-bf16 MFMA GEMM (48x416 @ 416x128) -> LayerNorm.
// One 512-thread WG per (b,i). K in two chunks (224 | 192). 8 waves, wave w
// owns N-tile w (cols 16w..16w+15); 3 M-tiles of 16 rows; acc = 3 x f32x4.
// Products per K-step: Ah*Wh + Al*Wh + Ah*Wl (error ~2^-15).
// ---------------------------------------------------------------------------
__global__ __launch_bounds__(512) void edge_kernel(
    const float* __restrict__ X,
    const int*   __restrict__ ridx, const int* __restrict__ chain,
    const float* __restrict__ Wpos, const float* __restrict__ bpos,
    const unsigned short* __restrict__ Wf,
    const float* __restrict__ gamma, const float* __restrict__ beta,
    const int*   __restrict__ eidx_i, float* __restrict__ Eout)
{
    __shared__ __align__(16) unsigned short fHL[2 * 48 * FSTRIDE];
    __shared__ float nbat[48][5][3];
    __shared__ float ctr[5][3];
    __shared__ int   dsel[48];
    __shared__ int   nbi[48];
    __shared__ float sumP[48][8];
    __shared__ float sqP[48][8];
    __shared__ float lnM[48], lnR[48];

    const int bi   = blockIdx.x;
    const int b    = bi >> 11;
    const int i    = bi & (LL - 1);
    const int tid  = threadIdx.x;
    const int w    = tid >> 6;
    const int lane = tid & 63;
    const float* Xb = X + (size_t)b * LL * 12;

    // ---- meta + center atoms ----
    if (tid < 48) {
        int j = eidx_i[(size_t)bi * KNN + tid];
        nbi[tid] = j;
        int off = ridx[b * LL + i] - ridx[b * LL + j];
        int sc  = (chain[b * LL + i] == chain[b * LL + j]);
        int d   = off + MAXREL;
        d = d < 0 ? 0 : (d > 2 * MAXREL ? 2 * MAXREL : d);
        dsel[tid] = sc ? d : (2 * MAXREL + 1);
    }
    if (tid >= 448 && tid < 452) {
        int a = tid - 448;                       // 0=Ca,1=N,2=C,3=O
        int src = (a == 0) ? 1 : ((a == 1) ? 0 : a);
        ctr[a][0] = Xb[i * 12 + src * 3 + 0];
        ctr[a][1] = Xb[i * 12 + src * 3 + 1];
        ctr[a][2] = Xb[i * 12 + src * 3 + 2];
    }
    __syncthreads();

    if (tid < 192) {
        int e = tid >> 2, a = tid & 3;
        int src = (a == 0) ? 1 : ((a == 1) ? 0 : a);
        int j = nbi[e];
        nbat[e][a][0] = Xb[j * 12 + src * 3 + 0];
        nbat[e][a][1] = Xb[j * 12 + src * 3 + 1];
        nbat[e][a][2] = Xb[j * 12 + src * 3 + 2];
    }
    __syncthreads();

    // virtual Cb
    if (tid < 48) {
        float bx = nbat[tid][0][0] - nbat[tid][1][0];
        float by = nbat[tid][0][1] - nbat[tid][1][1];
        float bz = nbat[tid][0][2] - nbat[tid][1][2];
        float cx = nbat[tid][2][0] - nbat[tid][0][0];
        float cy = nbat[tid][2][1] - nbat[tid][0][1];
        float cz = nbat[tid][2][2] - nbat[tid][0][2];
        float ax = by * cz - bz * cy;
        float ay = bz * cx - bx * cz;
        float az = bx * cy - by * cx;
        nbat[tid][4][0] = -0.58273431f * ax + 0.56802827f * bx - 0.54067466f * cx + nbat[tid][0][0];
        nbat[tid][4][1] = -0.58273431f * ay + 0.56802827f * by - 0.54067466f * cy + nbat[tid][0][1];
        nbat[tid][4][2] = -0.58273431f * az + 0.56802827f * bz - 0.54067466f * cz + nbat[tid][0][2];
    } else if (tid == 48) {
        float bx = ctr[0][0] - ctr[1][0];
        float by = ctr[0][1] - ctr[1][1];
        float bz = ctr[0][2] - ctr[1][2];
        float cx = ctr[2][0] - ctr[0][0];
        float cy = ctr[2][1] - ctr[0][1];
        float cz = ctr[2][2] - ctr[0][2];
        float ax = by * cz - bz * cy;
        float ay = bz * cx - bx * cz;
        float az = bx * cy - by * cx;
        ctr[4][0] = -0.58273431f * ax + 0.56802827f * bx - 0.54067466f * cx + ctr[0][0];
        ctr[4][1] = -0.58273431f * ay + 0.56802827f * by - 0.54067466f * cy + ctr[0][1];
        ctr[4][2] = -0.58273431f * az + 0.56802827f * bz - 0.54067466f * cz + ctr[0][2];
    }
    __syncthreads();

    // ---- chunk 0 features: positional (k 0..15) + RBF pairs 0..12 (k 16..223)
    for (int idx = tid; idx < 48 * 16; idx += 512) {
        int e = idx >> 4, p = idx & 15;
        float f = Wpos[dsel[e] * 16 + p] + bpos[p];
        unsigned short h, l;
        split_hi_lo(f, h, l);
        fHL[e * FSTRIDE + p]         = h;
        fHL[FLOFF + e * FSTRIDE + p] = l;
    }
    for (int idx = tid; idx < 48 * 13; idx += 512) {
        int e = idx / 13, pr = idx % 13;
        int A = pr / 5, Bv = pr % 5;
        int klocal = 16 + pr * 16;
        float dx = ctr[A][0] - nbat[e][Bv][0];
        float dy = ctr[A][1] - nbat[e][Bv][1];
        float dz = ctr[A][2] - nbat[e][Bv][2];
        float d  = sqrtf(dx * dx + dy * dy + dz * dz + 1e-6f);
        uint hw[8], lw[8];
        #pragma unroll
        for (int rp = 0; rp < 8; rp++) {
            float mu0 = 2.0f + 1.3333334f * (float)(2 * rp);
            float mu1 = 2.0f + 1.3333334f * (float)(2 * rp + 1);
            float t0 = (d - mu0) * 0.8f, t1 = (d - mu1) * 0.8f;
            float v0 = __expf(-t0 * t0), v1 = __expf(-t1 * t1);
            unsigned short h0, l0, h1, l1;
            split_hi_lo(v0, h0, l0); split_hi_lo(v1, h1, l1);
            hw[rp] = (uint)h0 | ((uint)h1 << 16);
            lw[rp] = (uint)l0 | ((uint)l1 << 16);
        }
        uint4* dh = (uint4*)&fHL[e * FSTRIDE + klocal];
        dh[0] = make_uint4(hw[0], hw[1], hw[2], hw[3]);
        dh[1] = make_uint4(hw[4], hw[5], hw[6], hw[7]);
        uint4* dl = (uint4*)&fHL[FLOFF + e * FSTRIDE + klocal];
        dl[0] = make_uint4(lw[0], lw[1], lw[2], lw[3]);
        dl[1] = make_uint4(lw[4], lw[5], lw[6], lw[7]);
    }
    __syncthreads();

    // ---- GEMM ----
    const unsigned short* aB = &fHL[(lane & 15) * FSTRIDE + ((lane >> 4) << 3)];
    const unsigned short* wB = Wf + (size_t)w * 512 + (size_t)lane * 8;
    f32x4 acc0 = {0.f, 0.f, 0.f, 0.f}, acc1 = acc0, acc2 = acc0;

    #pragma unroll
    for (int kt = 0; kt < 7; kt++) {                 // chunk 0: ktg = kt
        U16x8 wh, wl, a0h, a1h, a2h, a0l, a1l, a2l;
        wh.q  = *(const uint4*)(wB + kt * 4096);
        wl.q  = *(const uint4*)(wB + WFH_ELEMS + kt * 4096);
        a0h.q = *(const uint4*)(aB + kt * 32);
        a1h.q = *(const uint4*)(aB + 16 * FSTRIDE + kt * 32);
        a2h.q = *(const uint4*)(aB + 32 * FSTRIDE + kt * 32);
        a0l.q = *(const uint4*)(aB + FLOFF + kt * 32);
        a1l.q = *(const uint4*)(aB + FLOFF + 16 * FSTRIDE + kt * 32);
        a2l.q = *(const uint4*)(aB + FLOFF + 32 * FSTRIDE + kt * 32);
        acc0 = __builtin_amdgcn_mfma_f32_16x16x32_bf16(a0h.v, wh.v, acc0, 0, 0, 0);
        acc1 = __builtin_amdgcn_mfma_f32_16x16x32_bf16(a1h.v, wh.v, acc1, 0, 0, 0);
        acc2 = __builtin_amdgcn_mfma_f32_16x16x32_bf16(a2h.v, wh.v, acc2, 0, 0, 0);
        acc0 = __builtin_amdgcn_mfma_f32_16x16x32_bf16(a0l.v, wh.v, acc0, 0, 0, 0);
        acc1 = __builtin_amdgcn_mfma_f32_16x16x32_bf16(a1l.v, wh.v, acc1, 0, 0, 0);
        acc2 = __builtin_amdgcn_mfma_f32_16x16x32_bf16(a2l.v, wh.v, acc2, 0, 0, 0);
        acc0 = __builtin_amdgcn_mfma_f32_16x16x32_bf16(a0h.v, wl.v, acc0, 0, 0, 0);
        acc1 = __builtin_amdgcn_mfma_f32_16x16x32_bf16(a1h.v, wl.v, acc1, 0, 0, 0);
        acc2 = __builtin_amdgcn_mfma_f32_16x16x32_bf16(a2h.v, wl.v, acc2, 0, 0, 0);
    }
    __syncthreads();   // done reading chunk-0 features

    // ---- chunk 1 features: RBF pairs 13..24 (k 224..415 -> klocal 0..191)
    for (int idx = tid; idx < 48 * 12; idx += 512) {
        int e = idx / 12, prl = idx % 12;
        int pr = 13 + prl;
        int A = pr / 5, Bv = pr % 5;
        int klocal = prl * 16;
        float dx = ctr[A][0] - nbat[e][Bv][0];
        float dy = ctr[A][1] - nbat[e][Bv][1];
        float dz = ctr[A][2] - nbat[e][Bv][2];
        float d  = sqrtf(dx * dx + dy * dy + dz * dz + 1e-6f);
        uint hw[8], lw[8];
        #pragma unroll
        for (int rp = 0; rp < 8; rp++) {
            float mu0 = 2.0f + 1.3333334f * (float)(2 * rp);
            float mu1 = 2.0f + 1.3333334f * (float)(2 * rp + 1);
            float t0 = (d - mu0) * 0.8f, t1 = (d - mu1) * 0.8f;
            float v0 = __expf(-t0 * t0), v1 = __expf(-t1 * t1);
            unsigned short h0, l0, h1, l1;
            split_hi_lo(v0, h0, l0); split_hi_lo(v1, h1, l1);
            hw[rp] = (uint)h0 | ((uint)h1 << 16);
            lw[rp] = (uint)l0 | ((uint)l1 << 16);
        }
        uint4* dh = (uint4*)&fHL[e * FSTRIDE + klocal];
        dh[0] = make_uint4(hw[0], hw[1], hw[2], hw[3]);
        dh[1] = make_uint4(hw[4], hw[5], hw[6], hw[7]);
        uint4* dl = (uint4*)&fHL[FLOFF + e * FSTRIDE + klocal];
        dl[0] = make_uint4(lw[0], lw[1], lw[2], lw[3]);
        dl[1] = make_uint4(lw[4], lw[5], lw[6], lw[7]);
    }
    __syncthreads();

    #pragma unroll
    for (int kt = 0; kt < 6; kt++) {                 // chunk 1: ktg = 7 + kt
        U16x8 wh, wl, a0h, a1h, a2h, a0l, a1l, a2l;
        wh.q  = *(const uint4*)(wB + (7 + kt) * 4096);
        wl.q  = *(const uint4*)(wB + WFH_ELEMS + (7 + kt) * 4096);
        a0h.q = *(const uint4*)(aB + kt * 32);
        a1h.q = *(const uint4*)(aB + 16 * FSTRIDE + kt * 32);
        a2h.q = *(const uint4*)(aB + 32 * FSTRIDE + kt * 32);
        a0l.q = *(const uint4*)(aB + FLOFF + kt * 32);
        a1l.q = *(const uint4*)(aB + FLOFF + 16 * FSTRIDE + kt * 32);
        a2l.q = *(const uint4*)(aB + FLOFF + 32 * FSTRIDE + kt * 32);
        acc0 = __builtin_amdgcn_mfma_f32_16x16x32_bf16(a0h.v, wh.v, acc0, 0, 0, 0);
        acc1 = __builtin_amdgcn_mfma_f32_16x16x32_bf16(a1h.v, wh.v, acc1, 0, 0, 0);
        acc2 = __builtin_amdgcn_mfma_f32_16x16x32_bf16(a2h.v, wh.v, acc2, 0, 0, 0);
        acc0 = __builtin_amdgcn_mfma_f32_16x16x32_bf16(a0l.v, wh.v, acc0, 0, 0, 0);
        acc1 = __builtin_amdgcn_mfma_f32_16x16x32_bf16(a1l.v, wh.v, acc1, 0, 0, 0);
        acc2 = __builtin_amdgcn_mfma_f32_16x16x32_bf16(a2l.v, wh.v, acc2, 0, 0, 0);
        acc0 = __builtin_amdgcn_mfma_f32_16x16x32_bf16(a0h.v, wl.v, acc0, 0, 0, 0);
        acc1 = __builtin_amdgcn_mfma_f32_16x16x32_bf16(a1h.v, wl.v, acc1, 0, 0, 0);
        acc2 = __builtin_amdgcn_mfma_f32_16x16x32_bf16(a2h.v, wl.v, acc2, 0, 0, 0);
    }

    // ---- LayerNorm ----
    // C/D layout: row = mt*16 + (lane>>4)*4 + r, col = 16w + (lane&15)
    {
        float vals[3][4] = {{acc0[0], acc0[1], acc0[2], acc0[3]},
                            {acc1[0], acc1[1], acc1[2], acc1[3]},
                            {acc2[0], acc2[1], acc2[2], acc2[3]}};
        #pragma unroll
        for (int mt = 0; mt < 3; mt++) {
            #pragma unroll
            for (int r = 0; r < 4; r++) {
                float sm = vals[mt][r], sq = sm * sm;
                #pragma unroll
                for (int off = 1; off < 16; off <<= 1) {
                    sm += __shfl_xor(sm, off);
                    sq += __shfl_xor(sq, off);
                }
                if ((lane & 15) == 0) {
                    int row = mt * 16 + ((lane >> 4) << 2) + r;
                    sumP[row][w] = sm;
                    sqP[row][w]  = sq;
                }
            }
        }
        __syncthreads();
        if (tid < 48) {
            float s = 0.f, q = 0.f;
            #pragma unroll
            for (int t = 0; t < 8; t++) { s += sumP[tid][t]; q += sqP[tid][t]; }
            float m = s * 0.0078125f;
            lnM[tid] = m;
            lnR[tid] = rsqrtf(q * 0.0078125f - m * m + 1e-5f);
        }
        __syncthreads();

        const int col = (w << 4) + (lane & 15);
        const float g  = gamma[col];
        const float bt = beta[col];
        float* Eo = Eout + (size_t)bi * KNN * EDGE_D;
        #pragma unroll
        for (int mt = 0; mt < 3; mt++) {
            #pragma unroll
            for (int r = 0; r < 4; r++) {
                int row = mt * 16 + ((lane >> 4) << 2) + r;
                Eo[(size_t)row * EDGE_D + col] =
                    (vals[mt][r] - lnM[row]) * lnR[row] * g + bt;
            }
        }
    }
}

extern "C" void kernel_launch(void* const* d_in, const int* in_sizes, int n_in,
                              void* d_out, int out_size, void* d_ws, size_t ws_size,
                              hipStream_t stream) {
    const float* X     = (const float*)d_in[0];
    const float* mask  = (const float*)d_in[1];
    const int*   ridx  = (const int*)d_in[2];
    const int*   chain = (const int*)d_in[3];
    const float* Wpos  = (const float*)d_in[4];
    const float* bpos  = (const float*)d_in[5];
    const float* Wedge = (const float*)d_in[6];
    const float* gamma = (const float*)d_in[7];
    const float* beta  = (const float*)d_in[8];

    float* out    = (float*)d_out;
    float* Eout   = out;
    float* eidx_f = out + (size_t)BB * LL * KNN * EDGE_D;
    int*   eidx_i = (int*)d_ws;
    unsigned short* Wf = (unsigned short*)((char*)d_ws + EIDX_BYTES);

    hipLaunchKernelGGL(prep_kernel, dim3((WFH_ELEMS + 255) / 256), dim3(256), 0, stream,
                       Wedge, Wf);
    hipLaunchKernelGGL(knn_kernel, dim3(BB * LL), dim3(256), 0, stream,
                       X, mask, eidx_i, eidx_f);
    hipLaunchKernelGGL(edge_kernel, dim3(BB * LL), dim3(512), 0, stream,
                       X, ridx, chain, Wpos, bpos, Wf, gamma, beta, eidx_i, Eout);
}

// Round 4
// 242.269 us; speedup vs baseline: 2.9003x; 1.4886x over previous
//
#include <hip/hip_runtime.h>
#include <hip/hip_bf16.h>
#include <stdint.h>

#define BB 2
#define LL 2048
#define KNN 48
#define MAXREL 32
#define EDGE_D 128
#define FSTRIDE 232            // ushorts per feature row (chunk-local K max 224, +pad)
#define FLOFF   11136          // 48*FSTRIDE: element offset of the "lo" plane in fHL
#define WFH_ELEMS 53248        // 13*8*64*8: one plane of W fragments
#define EIDX_BYTES (BB*LL*KNN*4)

typedef unsigned long long u64;
typedef __bf16 bf16_t;
typedef bf16_t bf16x8 __attribute__((ext_vector_type(8)));
typedef float f32x4 __attribute__((ext_vector_type(4)));

union U16x8 { uint4 q; bf16x8 v; };

__device__ __forceinline__ u64 u64min(u64 a, u64 b) { return a < b ? a : b; }

__device__ __forceinline__ u64 shfl_xor_u64(u64 v, int m) {
    unsigned lo = __shfl_xor((unsigned)(v & 0xffffffffull), m);
    unsigned hi = __shfl_xor((unsigned)(v >> 32), m);
    return (((u64)hi) << 32) | lo;
}

// truncation split: f = hi + lo + eps, |eps| ~ 2^-16 |f|
__device__ __forceinline__ void split_hi_lo(float f, unsigned short& h, unsigned short& l) {
    unsigned bits = __float_as_uint(f);
    h = (unsigned short)(bits >> 16);
    float hf = __uint_as_float(bits & 0xffff0000u);
    float lo = f - hf;
    l = (unsigned short)(__float_as_uint(lo) >> 16);
}

// ---------------------------------------------------------------------------
// Kernel 0: split W_edge (416x128 f32) into bf16 hi/lo planes, pre-swizzled
// into mfma_f32_16x16x32_bf16 B-fragment order.
// ---------------------------------------------------------------------------
__global__ __launch_bounds__(256) void prep_kernel(const float* __restrict__ W,
                                                   unsigned short* __restrict__ Wf)
{
    int tid = blockIdx.x * 256 + threadIdx.x;
    if (tid >= WFH_ELEMS) return;
    int e    = tid & 7;
    int lane = (tid >> 3) & 63;
    int nt   = (tid >> 9) & 7;
    int ktg  = tid >> 12;
    int k    = ktg * 32 + ((lane >> 4) << 3) + e;
    int col  = (nt << 4) + (lane & 15);
    float f  = W[k * 128 + col];
    unsigned short h, l;
    split_hi_lo(f, h, l);
    Wf[tid]             = h;
    Wf[tid + WFH_ELEMS] = l;
}

// ---------------------------------------------------------------------------
// Kernel 1: exact kNN via 2-level histogram rank-48 threshold + compaction +
// one 64-element bitonic sort (wave 0). u64 key = dadj_bits<<32 | j, ascending
// order == jax.lax.top_k order incl. stable tie-break. Fallback to extract-min
// if >64 survivors (degenerate ties only).
// ---------------------------------------------------------------------------
__global__ __launch_bounds__(256) void knn_kernel(
    const float* __restrict__ X, const float* __restrict__ mask,
    int* __restrict__ eidx_i, float* __restrict__ eidx_f)
{
    const int bi   = blockIdx.x;
    const int b    = bi >> 11;
    const int i    = bi & (LL - 1);
    const int tid  = threadIdx.x;
    const int wv   = tid >> 6;
    const int lane = tid & 63;

    __shared__ int   hist[256];
    __shared__ int   ctrl[4];          // B, cbB, B2, m
    __shared__ int   cnt;
    __shared__ u64   list[64];
    __shared__ float wsh[4];
    __shared__ u64   wmin[2][4];       // fallback only

    const float* Xb = X + (size_t)b * LL * 12;
    const float* mb = mask + (size_t)b * LL;

    const float cax = Xb[i * 12 + 3];
    const float cay = Xb[i * 12 + 4];
    const float caz = Xb[i * 12 + 5];
    const float mi  = mb[i];

    float D[8], M2[8];
    float dmax = 0.0f;

    #pragma unroll
    for (int t = 0; t < 8; t++) {
        int j = (t << 8) + tid;
        float dx = Xb[j * 12 + 3] - cax;
        float dy = Xb[j * 12 + 4] - cay;
        float dz = Xb[j * 12 + 5] - caz;
        float s  = __fadd_rn(__fadd_rn(__fmul_rn(dx, dx), __fmul_rn(dy, dy)),
                             __fmul_rn(dz, dz));
        float m2 = __fmul_rn(mi, mb[j]);
        float d  = __fmul_rn(m2, sqrtf(__fadd_rn(s, 1e-6f)));
        D[t]  = d;
        M2[t] = m2;
        dmax  = fmaxf(dmax, d);
    }

    hist[tid] = 0;
    if (tid == 0) cnt = 0;

    #pragma unroll
    for (int off = 32; off; off >>= 1) dmax = fmaxf(dmax, __shfl_xor(dmax, off));
    if (lane == 0) wsh[wv] = dmax;
    __syncthreads();
    dmax = fmaxf(fmaxf(wsh[0], wsh[1]), fmaxf(wsh[2], wsh[3]));

    u64 key[8];
    #pragma unroll
    for (int t = 0; t < 8; t++) {
        int j = (t << 8) + tid;
        float dadj = __fadd_rn(D[t], __fmul_rn(1.0f - M2[t], dmax));
        key[t] = (((u64)__float_as_uint(dadj)) << 32) | (unsigned)j;
        atomicAdd(&hist[(int)(key[t] >> 55)], 1);     // pass-1 bin: f32 bits[30:23]
    }
    __syncthreads();

    // scan 1: find bin B with cum >= 48, and cbB = count before B
    if (wv == 0) {
        int h0 = hist[4 * lane], h1 = hist[4 * lane + 1];
        int h2 = hist[4 * lane + 2], h3 = hist[4 * lane + 3];
        int s = h0 + h1 + h2 + h3;
        int sc = s;
        #pragma unroll
        for (int off = 1; off < 64; off <<= 1) {
            int o = __shfl_up(sc, off);
            if (lane >= off) sc += o;
        }
        u64 ball = __ballot(sc >= KNN);
        int fl = __ffsll((unsigned long long)ball) - 1;
        if (lane == fl) {
            int cb = sc - s;
            int B, cbB;
            if      (cb + h0 >= KNN)           { B = 4 * lane;     cbB = cb; }
            else if (cb + h0 + h1 >= KNN)      { B = 4 * lane + 1; cbB = cb + h0; }
            else if (cb + h0 + h1 + h2 >= KNN) { B = 4 * lane + 2; cbB = cb + h0 + h1; }
            else                               { B = 4 * lane + 3; cbB = cb + h0 + h1 + h2; }
            ctrl[0] = B; ctrl[1] = cbB;
        }
    }
    __syncthreads();
    const int B = ctrl[0], cbB = ctrl[1];
    hist[tid] = 0;
    __syncthreads();

    #pragma unroll
    for (int t = 0; t < 8; t++) {
        if ((int)(key[t] >> 55) == B)
            atomicAdd(&hist[(int)(key[t] >> 47) & 255], 1);   // pass-2: bits[22:15]
    }
    __syncthreads();

    // scan 2: within bin B find sub-bin B2 with cbB + cum2 >= 48
    if (wv == 0) {
        const int T2 = KNN - cbB;
        int h0 = hist[4 * lane], h1 = hist[4 * lane + 1];
        int h2 = hist[4 * lane + 2], h3 = hist[4 * lane + 3];
        int s = h0 + h1 + h2 + h3;
        int sc = s;
        #pragma unroll
        for (int off = 1; off < 64; off <<= 1) {
            int o = __shfl_up(sc, off);
            if (lane >= off) sc += o;
        }
        u64 ball = __ballot(sc >= T2);
        int fl = __ffsll((unsigned long long)ball) - 1;
        if (lane == fl) {
            int cb = sc - s;
            int B2, cum;
            if      (cb + h0 >= T2)           { B2 = 4 * lane;     cum = cb + h0; }
            else if (cb + h0 + h1 >= T2)      { B2 = 4 * lane + 1; cum = cb + h0 + h1; }
            else if (cb + h0 + h1 + h2 >= T2) { B2 = 4 * lane + 2; cum = cb + h0 + h1 + h2; }
            else                              { B2 = 4 * lane + 3; cum = cb + h0 + h1 + h2 + h3; }
            ctrl[2] = B2; ctrl[3] = cbB + cum;   // m = survivors
        }
    }
    __syncthreads();
    const int B2 = ctrl[2], m = ctrl[3];

    if (m <= 64) {
        // compact survivors (order arbitrary; sort fixes it)
        #pragma unroll
        for (int t = 0; t < 8; t++) {
            int b1 = (int)(key[t] >> 55);
            int b2 = (int)(key[t] >> 47) & 255;
            if (b1 < B || (b1 == B && b2 <= B2)) {
                int p = atomicAdd(&cnt, 1);
                list[p] = key[t];
            }
        }
        __syncthreads();

        if (wv == 0) {
            u64 v = (lane < m) ? list[lane] : ~0ull;
            // bitonic sort, 64 lanes ascending
            #pragma unroll
            for (int k = 2; k <= 64; k <<= 1) {
                #pragma unroll
                for (int j = k >> 1; j > 0; j >>= 1) {
                    u64 o = shfl_xor_u64(v, j);
                    bool takemin = (((lane & k) == 0) == ((lane & j) == 0));
                    u64 mn = u64min(v, o);
                    u64 mx = v ^ o ^ mn;
                    v = takemin ? mn : mx;
                }
            }
            if (lane < KNN) {
                int j = (int)(v & 0xffffffffu);
                eidx_i[(size_t)bi * KNN + lane] = j;
                eidx_f[(size_t)bi * KNN + lane] = (float)j;
            }
        }
    } else {
        // degenerate ties: exact extract-min fallback (proven R2 path)
        for (int s = 0; s < KNN; s++) {
            u64 lmin = key[0];
            #pragma unroll
            for (int t = 1; t < 8; t++) lmin = u64min(lmin, key[t]);
            #pragma unroll
            for (int off = 1; off < 64; off <<= 1) lmin = u64min(lmin, shfl_xor_u64(lmin, off));
            if (lane == 0) wmin[s & 1][wv] = lmin;
            __syncthreads();
            u64 gmin = u64min(u64min(wmin[s & 1][0], wmin[s & 1][1]),
                              u64min(wmin[s & 1][2], wmin[s & 1][3]));
            if (tid == 0) {
                int j = (int)(gmin & 0xffffffffu);
                eidx_i[(size_t)bi * KNN + s] = j;
                eidx_f[(size_t)bi * KNN + s] = (float)j;
            }
            #pragma unroll
            for (int t = 0; t < 8; t++) if (key[t] == gmin) key[t] = ~0ull;
        }
    }
}

// ---------------------------------------------------------------------------
// Kernel 2: features -> split-bf16 MFMA GEMM (48x416 @ 416x128) -> LayerNorm.
// One 512-thread WG per (b,i). K in two chunks (224 | 192). 8 waves, wave w
// owns N-tile w; 3 M-tiles of 16 rows. Ah*Wh + Al*Wh + Ah*Wl per K-step.
// ---------------------------------------------------------------------------
__global__ __launch_bounds__(512) void edge_kernel(
    const float* __restrict__ X,
    const int*   __restrict__ ridx, const int* __restrict__ chain,
    const float* __restrict__ Wpos, const float* __restrict__ bpos,
    const unsigned short* __restrict__ Wf,
    const float* __restrict__ gamma, const float* __restrict__ beta,
    const int*   __restrict__ eidx_i, float* __restrict__ Eout)
{
    __shared__ __align__(16) unsigned short fHL[2 * 48 * FSTRIDE];
    __shared__ float nbat[48][5][3];
    __shared__ float ctr[5][3];
    __shared__ int   dsel[48];
    __shared__ int   nbi[48];
    __shared__ float sumP[48][8];
    __shared__ float sqP[48][8];
    __shared__ float lnM[48], lnR[48];

    const int bi   = blockIdx.x;
    const int b    = bi >> 11;
    const int i    = bi & (LL - 1);
    const int tid  = threadIdx.x;
    const int w    = tid >> 6;
    const int lane = tid & 63;
    const float* Xb = X + (size_t)b * LL * 12;

    // ---- meta + center atoms ----
    if (tid < 48) {
        int j = eidx_i[(size_t)bi * KNN + tid];
        nbi[tid] = j;
        int off = ridx[b * LL + i] - ridx[b * LL + j];
        int sc  = (chain[b * LL + i] == chain[b * LL + j]);
        int d   = off + MAXREL;
        d = d < 0 ? 0 : (d > 2 * MAXREL ? 2 * MAXREL : d);
        dsel[tid] = sc ? d : (2 * MAXREL + 1);
    }
    if (tid >= 448 && tid < 452) {
        int a = tid - 448;                       // 0=Ca,1=N,2=C,3=O
        int src = (a == 0) ? 1 : ((a == 1) ? 0 : a);
        ctr[a][0] = Xb[i * 12 + src * 3 + 0];
        ctr[a][1] = Xb[i * 12 + src * 3 + 1];
        ctr[a][2] = Xb[i * 12 + src * 3 + 2];
    }
    __syncthreads();

    if (tid < 192) {
        int e = tid >> 2, a = tid & 3;
        int src = (a == 0) ? 1 : ((a == 1) ? 0 : a);
        int j = nbi[e];
        nbat[e][a][0] = Xb[j * 12 + src * 3 + 0];
        nbat[e][a][1] = Xb[j * 12 + src * 3 + 1];
        nbat[e][a][2] = Xb[j * 12 + src * 3 + 2];
    }
    __syncthreads();

    // virtual Cb
    if (tid < 48) {
        float bx = nbat[tid][0][0] - nbat[tid][1][0];
        float by = nbat[tid][0][1] - nbat[tid][1][1];
        float bz = nbat[tid][0][2] - nbat[tid][1][2];
        float cx = nbat[tid][2][0] - nbat[tid][0][0];
        float cy = nbat[tid][2][1] - nbat[tid][0][1];
        float cz = nbat[tid][2][2] - nbat[tid][0][2];
        float ax = by * cz - bz * cy;
        float ay = bz * cx - bx * cz;
        float az = bx * cy - by * cx;
        nbat[tid][4][0] = -0.58273431f * ax + 0.56802827f * bx - 0.54067466f * cx + nbat[tid][0][0];
        nbat[tid][4][1] = -0.58273431f * ay + 0.56802827f * by - 0.54067466f * cy + nbat[tid][0][1];
        nbat[tid][4][2] = -0.58273431f * az + 0.56802827f * bz - 0.54067466f * cz + nbat[tid][0][2];
    } else if (tid == 48) {
        float bx = ctr[0][0] - ctr[1][0];
        float by = ctr[0][1] - ctr[1][1];
        float bz = ctr[0][2] - ctr[1][2];
        float cx = ctr[2][0] - ctr[0][0];
        float cy = ctr[2][1] - ctr[0][1];
        float cz = ctr[2][2] - ctr[0][2];
        float ax = by * cz - bz * cy;
        float ay = bz * cx - bx * cz;
        float az = bx * cy - by * cx;
        ctr[4][0] = -0.58273431f * ax + 0.56802827f * bx - 0.54067466f * cx + ctr[0][0];
        ctr[4][1] = -0.58273431f * ay + 0.56802827f * by - 0.54067466f * cy + ctr[0][1];
        ctr[4][2] = -0.58273431f * az + 0.56802827f * bz - 0.54067466f * cz + ctr[0][2];
    }
    __syncthreads();

    // ---- chunk 0 features: positional (k 0..15) + RBF pairs 0..12 (k 16..223)
    for (int idx = tid; idx < 48 * 16; idx += 512) {
        int e = idx >> 4, p = idx & 15;
        float f = Wpos[dsel[e] * 16 + p] + bpos[p];
        unsigned short h, l;
        split_hi_lo(f, h, l);
        fHL[e * FSTRIDE + p]         = h;
        fHL[FLOFF + e * FSTRIDE + p] = l;
    }
    for (int idx = tid; idx < 48 * 16; idx += 512) {
        int e = idx >> 4, pr = idx & 15;
        if (pr < 13) {
            int A = pr / 5, Bv = pr % 5;
            int klocal = 16 + pr * 16;
            float dx = ctr[A][0] - nbat[e][Bv][0];
            float dy = ctr[A][1] - nbat[e][Bv][1];
            float dz = ctr[A][2] - nbat[e][Bv][2];
            float d  = sqrtf(dx * dx + dy * dy + dz * dz + 1e-6f);
            uint hw[8], lw[8];
            #pragma unroll
            for (int rp = 0; rp < 8; rp++) {
                float mu0 = 2.0f + 1.3333334f * (float)(2 * rp);
                float mu1 = 2.0f + 1.3333334f * (float)(2 * rp + 1);
                float t0 = (d - mu0) * 0.8f, t1 = (d - mu1) * 0.8f;
                float v0 = __expf(-t0 * t0), v1 = __expf(-t1 * t1);
                unsigned short h0, l0, h1, l1;
                split_hi_lo(v0, h0, l0); split_hi_lo(v1, h1, l1);
                hw[rp] = (uint)h0 | ((uint)h1 << 16);
                lw[rp] = (uint)l0 | ((uint)l1 << 16);
            }
            uint4* dh = (uint4*)&fHL[e * FSTRIDE + klocal];
            dh[0] = make_uint4(hw[0], hw[1], hw[2], hw[3]);
            dh[1] = make_uint4(hw[4], hw[5], hw[6], hw[7]);
            uint4* dl = (uint4*)&fHL[FLOFF + e * FSTRIDE + klocal];
            dl[0] = make_uint4(lw[0], lw[1], lw[2], lw[3]);
            dl[1] = make_uint4(lw[4], lw[5], lw[6], lw[7]);
        }
    }
    __syncthreads();

    // ---- GEMM chunk 0 ----
    const unsigned short* aB = &fHL[(lane & 15) * FSTRIDE + ((lane >> 4) << 3)];
    const unsigned short* wB = Wf + (size_t)w * 512 + (size_t)lane * 8;
    f32x4 acc0 = {0.f, 0.f, 0.f, 0.f}, acc1 = acc0, acc2 = acc0;

    #pragma unroll
    for (int kt = 0; kt < 7; kt++) {
        U16x8 wh, wl, a0h, a1h, a2h, a0l, a1l, a2l;
        wh.q  = *(const uint4*)(wB + kt * 4096);
        wl.q  = *(const uint4*)(wB + WFH_ELEMS + kt * 4096);
        a0h.q = *(const uint4*)(aB + kt * 32);
        a1h.q = *(const uint4*)(aB + 16 * FSTRIDE + kt * 32);
        a2h.q = *(const uint4*)(aB + 32 * FSTRIDE + kt * 32);
        a0l.q = *(const uint4*)(aB + FLOFF + kt * 32);
        a1l.q = *(const uint4*)(aB + FLOFF + 16 * FSTRIDE + kt * 32);
        a2l.q = *(const uint4*)(aB + FLOFF + 32 * FSTRIDE + kt * 32);
        acc0 = __builtin_amdgcn_mfma_f32_16x16x32_bf16(a0h.v, wh.v, acc0, 0, 0, 0);
        acc1 = __builtin_amdgcn_mfma_f32_16x16x32_bf16(a1h.v, wh.v, acc1, 0, 0, 0);
        acc2 = __builtin_amdgcn_mfma_f32_16x16x32_bf16(a2h.v, wh.v, acc2, 0, 0, 0);
        acc0 = __builtin_amdgcn_mfma_f32_16x16x32_bf16(a0l.v, wh.v, acc0, 0, 0, 0);
        acc1 = __builtin_amdgcn_mfma_f32_16x16x32_bf16(a1l.v, wh.v, acc1, 0, 0, 0);
        acc2 = __builtin_amdgcn_mfma_f32_16x16x32_bf16(a2l.v, wh.v, acc2, 0, 0, 0);
        acc0 = __builtin_amdgcn_mfma_f32_16x16x32_bf16(a0h.v, wl.v, acc0, 0, 0, 0);
        acc1 = __builtin_amdgcn_mfma_f32_16x16x32_bf16(a1h.v, wl.v, acc1, 0, 0, 0);
        acc2 = __builtin_amdgcn_mfma_f32_16x16x32_bf16(a2h.v, wl.v, acc2, 0, 0, 0);
    }
    __syncthreads();   // done reading chunk-0 features

    // ---- chunk 1 features: RBF pairs 13..24 (k 224..415 -> klocal 0..191)
    for (int idx = tid; idx < 48 * 16; idx += 512) {
        int e = idx >> 4, prl = idx & 15;
        if (prl < 12) {
            int pr = 13 + prl;
            int A = pr / 5, Bv = pr % 5;
            int klocal = prl * 16;
            float dx = ctr[A][0] - nbat[e][Bv][0];
            float dy = ctr[A][1] - nbat[e][Bv][1];
            float dz = ctr[A][2] - nbat[e][Bv][2];
            float d  = sqrtf(dx * dx + dy * dy + dz * dz + 1e-6f);
            uint hw[8], lw[8];
            #pragma unroll
            for (int rp = 0; rp < 8; rp++) {
                float mu0 = 2.0f + 1.3333334f * (float)(2 * rp);
                float mu1 = 2.0f + 1.3333334f * (float)(2 * rp + 1);
                float t0 = (d - mu0) * 0.8f, t1 = (d - mu1) * 0.8f;
                float v0 = __expf(-t0 * t0), v1 = __expf(-t1 * t1);
                unsigned short h0, l0, h1, l1;
                split_hi_lo(v0, h0, l0); split_hi_lo(v1, h1, l1);
                hw[rp] = (uint)h0 | ((uint)h1 << 16);
                lw[rp] = (uint)l0 | ((uint)l1 << 16);
            }
            uint4* dh = (uint4*)&fHL[e * FSTRIDE + klocal];
            dh[0] = make_uint4(hw[0], hw[1], hw[2], hw[3]);
            dh[1] = make_uint4(hw[4], hw[5], hw[6], hw[7]);
            uint4* dl = (uint4*)&fHL[FLOFF + e * FSTRIDE + klocal];
            dl[0] = make_uint4(lw[0], lw[1], lw[2], lw[3]);
            dl[1] = make_uint4(lw[4], lw[5], lw[6], lw[7]);
        }
    }
    __syncthreads();

    #pragma unroll
    for (int kt = 0; kt < 6; kt++) {
        U16x8 wh, wl, a0h, a1h, a2h, a0l, a1l, a2l;
        wh.q  = *(const uint4*)(wB + (7 + kt) * 4096);
        wl.q  = *(const uint4*)(wB + WFH_ELEMS + (7 + kt) * 4096);
        a0h.q = *(const uint4*)(aB + kt * 32);
        a1h.q = *(const uint4*)(aB + 16 * FSTRIDE + kt * 32);
        a2h.q = *(const uint4*)(aB + 32 * FSTRIDE + kt * 32);
        a0l.q = *(const uint4*)(aB + FLOFF + kt * 32);
        a1l.q = *(const uint4*)(aB + FLOFF + 16 * FSTRIDE + kt * 32);
        a2l.q = *(const uint4*)(aB + FLOFF + 32 * FSTRIDE + kt * 32);
        acc0 = __builtin_amdgcn_mfma_f32_16x16x32_bf16(a0h.v, wh.v, acc0, 0, 0, 0);
        acc1 = __builtin_amdgcn_mfma_f32_16x16x32_bf16(a1h.v, wh.v, acc1, 0, 0, 0);
        acc2 = __builtin_amdgcn_mfma_f32_16x16x32_bf16(a2h.v, wh.v, acc2, 0, 0, 0);
        acc0 = __builtin_amdgcn_mfma_f32_16x16x32_bf16(a0l.v, wh.v, acc0, 0, 0, 0);
        acc1 = __builtin_amdgcn_mfma_f32_16x16x32_bf16(a1l.v, wh.v, acc1, 0, 0, 0);
        acc2 = __builtin_amdgcn_mfma_f32_16x16x32_bf16(a2l.v, wh.v, acc2, 0, 0, 0);
        acc0 = __builtin_amdgcn_mfma_f32_16x16x32_bf16(a0h.v, wl.v, acc0, 0, 0, 0);
        acc1 = __builtin_amdgcn_mfma_f32_16x16x32_bf16(a1h.v, wl.v, acc1, 0, 0, 0);
        acc2 = __builtin_amdgcn_mfma_f32_16x16x32_bf16(a2h.v, wl.v, acc2, 0, 0, 0);
    }

    // ---- LayerNorm ----
    // C/D layout: row = mt*16 + (lane>>4)*4 + r, col = 16w + (lane&15)
    {
        float vals[3][4] = {{acc0[0], acc0[1], acc0[2], acc0[3]},
                            {acc1[0], acc1[1], acc1[2], acc1[3]},
                            {acc2[0], acc2[1], acc2[2], acc2[3]}};
        #pragma unroll
        for (int mt = 0; mt < 3; mt++) {
            #pragma unroll
            for (int r = 0; r < 4; r++) {
                float sm = vals[mt][r], sq = sm * sm;
                #pragma unroll
                for (int off = 1; off < 16; off <<= 1) {
                    sm += __shfl_xor(sm, off);
                    sq += __shfl_xor(sq, off);
                }
                if ((lane & 15) == 0) {
                    int row = mt * 16 + ((lane >> 4) << 2) + r;
                    sumP[row][w] = sm;
                    sqP[row][w]  = sq;
                }
            }
        }
        __syncthreads();
        if (tid < 48) {
            float s = 0.f, q = 0.f;
            #pragma unroll
            for (int t = 0; t < 8; t++) { s += sumP[tid][t]; q += sqP[tid][t]; }
            float m = s * 0.0078125f;
            lnM[tid] = m;
            lnR[tid] = rsqrtf(q * 0.0078125f - m * m + 1e-5f);
        }
        __syncthreads();

        const int col = (w << 4) + (lane & 15);
        const float g  = gamma[col];
        const float bt = beta[col];
        float* Eo = Eout + (size_t)bi * KNN * EDGE_D;
        #pragma unroll
        for (int mt = 0; mt < 3; mt++) {
            #pragma unroll
            for (int r = 0; r < 4; r++) {
                int row = mt * 16 + ((lane >> 4) << 2) + r;
                Eo[(size_t)row * EDGE_D + col] =
                    (vals[mt][r] - lnM[row]) * lnR[row] * g + bt;
            }
        }
    }
}

extern "C" void kernel_launch(void* const* d_in, const int* in_sizes, int n_in,
                              void* d_out, int out_size, void* d_ws, size_t ws_size,
                              hipStream_t stream) {
    const float* X     = (const float*)d_in[0];
    const float* mask  = (const float*)d_in[1];
    const int*   ridx  = (const int*)d_in[2];
    const int*   chain = (const int*)d_in[3];
    const float* Wpos  = (const float*)d_in[4];
    const float* bpos  = (const float*)d_in[5];
    const float* Wedge = (const float*)d_in[6];
    const float* gamma = (const float*)d_in[7];
    const float* beta  = (const float*)d_in[8];

    float* out    = (float*)d_out;
    float* Eout   = out;
    float* eidx_f = out + (size_t)BB * LL * KNN * EDGE_D;
    int*   eidx_i = (int*)d_ws;
    unsigned short* Wf = (unsigned short*)((char*)d_ws + EIDX_BYTES);

    hipLaunchKernelGGL(prep_kernel, dim3((WFH_ELEMS + 255) / 256), dim3(256), 0, stream,
                       Wedge, Wf);
    hipLaunchKernelGGL(knn_kernel, dim3(BB * LL), dim3(256), 0, stream,
                       X, mask, eidx_i, eidx_f);
    hipLaunchKernelGGL(edge_kernel, dim3(BB * LL), dim3(512), 0, stream,
                       X, ridx, chain, Wpos, bpos, Wf, gamma, beta, eidx_i, Eout);
}

// Round 6
// 225.708 us; speedup vs baseline: 3.1131x; 1.0734x over previous
//
#include <hip/hip_runtime.h>
#include <hip/hip_bf16.h>
#include <stdint.h>

#define BB 2
#define LL 2048
#define KNN 48
#define MAXREL 32
#define EDGE_D 128
#define WFH_ELEMS 53248        // 13*8*64*8: one plane of W fragments
#define EIDX_BYTES (BB*LL*KNN*4)
// A-fragment LDS geometry: [plane(2)][mt(3)][kt(7)][65 frags] of 16B frags
#define KT_PAD 65
#define PM_FRAGS (7 * KT_PAD)          // 455 frags per (plane,mt)
#define TOT_FRAGS (2 * 3 * PM_FRAGS)   // 2730 frags = 43680 B

typedef unsigned long long u64;
typedef __bf16 bf16_t;
typedef bf16_t bf16x8 __attribute__((ext_vector_type(8)));
typedef float f32x4 __attribute__((ext_vector_type(4)));

union U16x8 { uint4 q; bf16x8 v; };

__device__ __forceinline__ u64 u64min(u64 a, u64 b) { return a < b ? a : b; }

__device__ __forceinline__ u64 shfl_xor_u64(u64 v, int m) {
    unsigned lo = __shfl_xor((unsigned)(v & 0xffffffffull), m);
    unsigned hi = __shfl_xor((unsigned)(v >> 32), m);
    return (((u64)hi) << 32) | lo;
}

// truncation split: f = hi + lo + eps, |eps| ~ 2^-16 |f|
__device__ __forceinline__ void split_hi_lo(float f, unsigned short& h, unsigned short& l) {
    unsigned bits = __float_as_uint(f);
    h = (unsigned short)(bits >> 16);
    float hf = __uint_as_float(bits & 0xffff0000u);
    float lo = f - hf;
    l = (unsigned short)(__float_as_uint(lo) >> 16);
}

// ---------------------------------------------------------------------------
// Kernel 0: split W_edge (416x128 f32) into bf16 hi/lo planes, pre-swizzled
// into mfma_f32_16x16x32_bf16 B-fragment order.
// ---------------------------------------------------------------------------
__global__ __launch_bounds__(256) void prep_kernel(const float* __restrict__ W,
                                                   unsigned short* __restrict__ Wf)
{
    int tid = blockIdx.x * 256 + threadIdx.x;
    if (tid >= WFH_ELEMS) return;
    int e    = tid & 7;
    int lane = (tid >> 3) & 63;
    int nt   = (tid >> 9) & 7;
    int ktg  = tid >> 12;
    int k    = ktg * 32 + ((lane >> 4) << 3) + e;
    int col  = (nt << 4) + (lane & 15);
    float f  = W[k * 128 + col];
    unsigned short h, l;
    split_hi_lo(f, h, l);
    Wf[tid]             = h;
    Wf[tid + WFH_ELEMS] = l;
}

// ---------------------------------------------------------------------------
// Kernel 1: exact kNN via LINEAR-VALUE histogram rank-48 select + 64-key
// bitonic sort. Key = dadj_bits<<32 | j (ascending == jax.lax.top_k order,
// stable tie-break). Linear binning over [dmin,dmax] is order-monotone and
// spreads ~8 keys/bin (low LDS-atomic contention); one pass usually yields
// <=64 survivors. Second refined pass, then exact extract-min fallback.
// ---------------------------------------------------------------------------
__global__ __launch_bounds__(256) void knn_kernel(
    const float* __restrict__ X, const float* __restrict__ mask,
    int* __restrict__ eidx_i, float* __restrict__ eidx_f)
{
    const int bi   = blockIdx.x;
    const int b    = bi >> 11;
    const int i    = bi & (LL - 1);
    const int tid  = threadIdx.x;
    const int wv   = tid >> 6;
    const int lane = tid & 63;

    __shared__ int   hist[256];
    __shared__ int   ctrl[4];
    __shared__ int   cnt;
    __shared__ u64   list[64];
    __shared__ float wshA[4], wshB[4];
    __shared__ u64   wmin[2][4];       // fallback only

    const float* Xb = X + (size_t)b * LL * 12;
    const float* mb = mask + (size_t)b * LL;

    const float cax = Xb[i * 12 + 3];
    const float cay = Xb[i * 12 + 4];
    const float caz = Xb[i * 12 + 5];
    const float mi  = mb[i];

    float D[8], M2[8];
    float dmax = 0.0f;

    #pragma unroll
    for (int t = 0; t < 8; t++) {
        int j = (t << 8) + tid;
        float dx = Xb[j * 12 + 3] - cax;
        float dy = Xb[j * 12 + 4] - cay;
        float dz = Xb[j * 12 + 5] - caz;
        float s  = __fadd_rn(__fadd_rn(__fmul_rn(dx, dx), __fmul_rn(dy, dy)),
                             __fmul_rn(dz, dz));
        float m2 = __fmul_rn(mi, mb[j]);
        float d  = __fmul_rn(m2, sqrtf(__fadd_rn(s, 1e-6f)));
        D[t]  = d;
        M2[t] = m2;
        dmax  = fmaxf(dmax, d);
    }

    hist[tid] = 0;
    if (tid == 0) cnt = 0;

    #pragma unroll
    for (int off = 32; off; off >>= 1) dmax = fmaxf(dmax, __shfl_xor(dmax, off));
    if (lane == 0) wshA[wv] = dmax;
    __syncthreads();
    dmax = fmaxf(fmaxf(wshA[0], wshA[1]), fmaxf(wshA[2], wshA[3]));

    u64 key[8];
    float dadj[8];
    float dmin = 3.4e38f;
    #pragma unroll
    for (int t = 0; t < 8; t++) {
        int j = (t << 8) + tid;
        float da = __fadd_rn(D[t], __fmul_rn(1.0f - M2[t], dmax));
        dadj[t] = da;
        key[t] = (((u64)__float_as_uint(da)) << 32) | (unsigned)j;
        dmin = fminf(dmin, da);
    }
    #pragma unroll
    for (int off = 32; off; off >>= 1) dmin = fminf(dmin, __shfl_xor(dmin, off));
    if (lane == 0) wshB[wv] = dmin;
    __syncthreads();
    dmin = fminf(fminf(wshB[0], wshB[1]), fminf(wshB[2], wshB[3]));

    const float range = dmax - dmin;
    const float scale = (range > 1e-35f) ? (255.0f / range) : 0.0f;

    int bin[8];
    #pragma unroll
    for (int t = 0; t < 8; t++) {
        int bb = (int)((dadj[t] - dmin) * scale);
        bin[t] = bb > 255 ? 255 : bb;
        atomicAdd(&hist[bin[t]], 1);
    }
    __syncthreads();

    // scan 1: first bin B where cumulative >= KNN
    if (wv == 0) {
        int h0 = hist[4 * lane], h1 = hist[4 * lane + 1];
        int h2 = hist[4 * lane + 2], h3 = hist[4 * lane + 3];
        int s = h0 + h1 + h2 + h3;
        int sc = s;
        #pragma unroll
        for (int off = 1; off < 64; off <<= 1) {
            int o = __shfl_up(sc, off);
            if (lane >= off) sc += o;
        }
        u64 ball = __ballot(sc >= KNN);
        int fl = __ffsll((unsigned long long)ball) - 1;
        if (lane == fl) {
            int cb = sc - s;
            int B, cbB, m1;
            if      (cb + h0 >= KNN)           { B = 4*lane;   cbB = cb;          m1 = cb+h0; }
            else if (cb + h0 + h1 >= KNN)      { B = 4*lane+1; cbB = cb+h0;       m1 = cb+h0+h1; }
            else if (cb + h0 + h1 + h2 >= KNN) { B = 4*lane+2; cbB = cb+h0+h1;    m1 = cb+h0+h1+h2; }
            else                               { B = 4*lane+3; cbB = cb+h0+h1+h2; m1 = cb+h0+h1+h2+h3; }
            ctrl[0] = B; ctrl[1] = cbB; ctrl[2] = m1;
        }
    }
    __syncthreads();
    const int B = ctrl[0], cbB = ctrl[1], m1 = ctrl[2];

    if (m1 <= 64) {
        #pragma unroll
        for (int t = 0; t < 8; t++) {
            if (bin[t] <= B) { int p = atomicAdd(&cnt, 1); list[p] = key[t]; }
        }
        __syncthreads();
        if (wv == 0) {
            u64 v = (lane < m1) ? list[lane] : ~0ull;
            #pragma unroll
            for (int k = 2; k <= 64; k <<= 1)
                #pragma unroll
                for (int j = k >> 1; j > 0; j >>= 1) {
                    u64 o = shfl_xor_u64(v, j);
                    bool takemin = (((lane & k) == 0) == ((lane & j) == 0));
                    u64 mn = u64min(v, o);
                    u64 mx = v ^ o ^ mn;
                    v = takemin ? mn : mx;
                }
            if (lane < KNN) {
                int j = (int)(v & 0xffffffffu);
                eidx_i[(size_t)bi * KNN + lane] = j;
                eidx_f[(size_t)bi * KNN + lane] = (float)j;
            }
        }
        return;
    }

    // pass 2: refine within bin B
    hist[tid] = 0;
    __syncthreads();
    const float width  = range * (1.0f / 255.0f);
    const float b_lo   = dmin + (float)B * width;
    const float scale2 = (width > 1e-35f) ? (255.0f / width) : 0.0f;
    int bin2[8];
    #pragma unroll
    for (int t = 0; t < 8; t++) {
        if (bin[t] == B) {
            int bb = (int)((dadj[t] - b_lo) * scale2);
            bb = bb < 0 ? 0 : (bb > 255 ? 255 : bb);
            bin2[t] = bb;
            atomicAdd(&hist[bb], 1);
        } else bin2[t] = 1 << 30;
    }
    __syncthreads();

    if (wv == 0) {
        const int T2 = KNN - cbB;
        int h0 = hist[4 * lane], h1 = hist[4 * lane + 1];
        int h2 = hist[4 * lane + 2], h3 = hist[4 * lane + 3];
        int s = h0 + h1 + h2 + h3;
        int sc = s;
        #pragma unroll
        for (int off = 1; off < 64; off <<= 1) {
            int o = __shfl_up(sc, off);
            if (lane >= off) sc += o;
        }
        u64 ball = __ballot(sc >= T2);
        int fl = __ffsll((unsigned long long)ball) - 1;
        if (lane == fl) {
            int cb = sc - s;
            int B2, cum;
            if      (cb + h0 >= T2)           { B2 = 4*lane;   cum = cb+h0; }
            else if (cb + h0 + h1 >= T2)      { B2 = 4*lane+1; cum = cb+h0+h1; }
            else if (cb + h0 + h1 + h2 >= T2) { B2 = 4*lane+2; cum = cb+h0+h1+h2; }
            else                              { B2 = 4*lane+3; cum = cb+h0+h1+h2+h3; }
            ctrl[2] = B2; ctrl[3] = cbB + cum;
        }
    }
    __syncthreads();
    const int B2 = ctrl[2], m2 = ctrl[3];

    if (m2 <= 64) {
        #pragma unroll
        for (int t = 0; t < 8; t++) {
            if (bin[t] < B || (bin[t] == B && bin2[t] <= B2)) {
                int p = atomicAdd(&cnt, 1); list[p] = key[t];
            }
        }
        __syncthreads();
        if (wv == 0) {
            u64 v = (lane < m2) ? list[lane] : ~0ull;
            #pragma unroll
            for (int k = 2; k <= 64; k <<= 1)
                #pragma unroll
                for (int j = k >> 1; j > 0; j >>= 1) {
                    u64 o = shfl_xor_u64(v, j);
                    bool takemin = (((lane & k) == 0) == ((lane & j) == 0));
                    u64 mn = u64min(v, o);
                    u64 mx = v ^ o ^ mn;
                    v = takemin ? mn : mx;
                }
            if (lane < KNN) {
                int j = (int)(v & 0xffffffffu);
                eidx_i[(size_t)bi * KNN + lane] = j;
                eidx_f[(size_t)bi * KNN + lane] = (float)j;
            }
        }
        return;
    }

    // degenerate ties: exact extract-min fallback
    for (int s = 0; s < KNN; s++) {
        u64 lmin = key[0];
        #pragma unroll
        for (int t = 1; t < 8; t++) lmin = u64min(lmin, key[t]);
        #pragma unroll
        for (int off = 1; off < 64; off <<= 1) lmin = u64min(lmin, shfl_xor_u64(lmin, off));
        if (lane == 0) wmin[s & 1][wv] = lmin;
        __syncthreads();
        u64 gmin = u64min(u64min(wmin[s & 1][0], wmin[s & 1][1]),
                          u64min(wmin[s & 1][2], wmin[s & 1][3]));
        if (tid == 0) {
            int j = (int)(gmin & 0xffffffffu);
            eidx_i[(size_t)bi * KNN + s] = j;
            eidx_f[(size_t)bi * KNN + s] = (float)j;
        }
        #pragma unroll
        for (int t = 0; t < 8; t++) if (key[t] == gmin) key[t] = ~0ull;
    }
}

// ---------------------------------------------------------------------------
// Kernel 2: features -> split-bf16 MFMA GEMM (48x416 @ 416x128) -> LayerNorm.
// One 512-thread WG per (b,i), __launch_bounds__(512,6): VGPR cap ~85,
// 3 WG/CU (LDS 50.4 KB). W fragments stream from L2 with an explicit 1-deep
// software pipeline (next kt's wh/wl issued before current kt's MFMAs; first
// load issued before the feature phase) -- no big register cache, no spills.
// A features stored in MFMA fragment order in LDS: frag[(plane*3+mt)*455 +
// kt*65 + lane] (16B) -> lane-consecutive ds_read_b128, zero bank conflicts.
// ---------------------------------------------------------------------------
__global__ __launch_bounds__(512, 6) void edge_kernel(
    const float* __restrict__ X,
    const int*   __restrict__ ridx, const int* __restrict__ chain,
    const float* __restrict__ Wpos, const float* __restrict__ bpos,
    const unsigned short* __restrict__ Wf,
    const float* __restrict__ gamma, const float* __restrict__ beta,
    const int*   __restrict__ eidx_i, float* __restrict__ Eout)
{
    __shared__ __align__(16) uint4 frag[TOT_FRAGS];
    __shared__ float nbat[48][5][3];
    __shared__ float ctr[5][3];
    __shared__ int   dsel[48];
    __shared__ int   nbi[48];
    __shared__ float sumP[48][8];
    __shared__ float sqP[48][8];
    __shared__ float lnM[48], lnR[48];

    const int bi   = blockIdx.x;
    const int b    = bi >> 11;
    const int i    = bi & (LL - 1);
    const int tid  = threadIdx.x;
    const int w    = tid >> 6;
    const int lane = tid & 63;
    const float* Xb = X + (size_t)b * LL * 12;

    const unsigned short* wB = Wf + (size_t)w * 512 + (size_t)lane * 8;

    // issue kt=0 W loads now: L2 latency hides under the feature phase
    uint4 whc = *(const uint4*)(wB);
    uint4 wlc = *(const uint4*)(wB + WFH_ELEMS);
    uint4 whn, wln;

    // ---- meta + center atoms ----
    if (tid < 48) {
        int j = eidx_i[(size_t)bi * KNN + tid];
        nbi[tid] = j;
        int off = ridx[b * LL + i] - ridx[b * LL + j];
        int sc  = (chain[b * LL + i] == chain[b * LL + j]);
        int d   = off + MAXREL;
        d = d < 0 ? 0 : (d > 2 * MAXREL ? 2 * MAXREL : d);
        dsel[tid] = sc ? d : (2 * MAXREL + 1);
    }
    if (tid >= 448 && tid < 452) {
        int a = tid - 448;                       // 0=Ca,1=N,2=C,3=O
        int src = (a == 0) ? 1 : ((a == 1) ? 0 : a);
        ctr[a][0] = Xb[i * 12 + src * 3 + 0];
        ctr[a][1] = Xb[i * 12 + src * 3 + 1];
        ctr[a][2] = Xb[i * 12 + src * 3 + 2];
    }
    __syncthreads();

    if (tid < 192) {
        int e = tid >> 2, a = tid & 3;
        int src = (a == 0) ? 1 : ((a == 1) ? 0 : a);
        int j = nbi[e];
        nbat[e][a][0] = Xb[j * 12 + src * 3 + 0];
        nbat[e][a][1] = Xb[j * 12 + src * 3 + 1];
        nbat[e][a][2] = Xb[j * 12 + src * 3 + 2];
    }
    __syncthreads();

    // virtual Cb
    if (tid < 48) {
        float bx = nbat[tid][0][0] - nbat[tid][1][0];
        float by = nbat[tid][0][1] - nbat[tid][1][1];
        float bz = nbat[tid][0][2] - nbat[tid][1][2];
        float cx = nbat[tid][2][0] - nbat[tid][0][0];
        float cy = nbat[tid][2][1] - nbat[tid][0][1];
        float cz = nbat[tid][2][2] - nbat[tid][0][2];
        float ax = by * cz - bz * cy;
        float ay = bz * cx - bx * cz;
        float az = bx * cy - by * cx;
        nbat[tid][4][0] = -0.58273431f * ax + 0.56802827f * bx - 0.54067466f * cx + nbat[tid][0][0];
        nbat[tid][4][1] = -0.58273431f * ay + 0.56802827f * by - 0.54067466f * cy + nbat[tid][0][1];
        nbat[tid][4][2] = -0.58273431f * az + 0.56802827f * bz - 0.54067466f * cz + nbat[tid][0][2];
    } else if (tid == 48) {
        float bx = ctr[0][0] - ctr[1][0];
        float by = ctr[0][1] - ctr[1][1];
        float bz = ctr[0][2] - ctr[1][2];
        float cx = ctr[2][0] - ctr[0][0];
        float cy = ctr[2][1] - ctr[0][1];
        float cz = ctr[2][2] - ctr[0][2];
        float ax = by * cz - bz * cy;
        float ay = bz * cx - bx * cz;
        float az = bx * cy - by * cx;
        ctr[4][0] = -0.58273431f * ax + 0.56802827f * bx - 0.54067466f * cx + ctr[0][0];
        ctr[4][1] = -0.58273431f * ay + 0.56802827f * by - 0.54067466f * cy + ctr[0][1];
        ctr[4][2] = -0.58273431f * az + 0.56802827f * bz - 0.54067466f * cz + ctr[0][2];
    }
    __syncthreads();

    unsigned short* fS = (unsigned short*)frag;   // scalar view

    // ---- chunk 0: positional (klocal 0..15) + RBF pairs 0..12 (klocal 16..223)
    for (int idx = tid; idx < 48 * 16; idx += 512) {
        int e = idx >> 4, p = idx & 15;
        int mt = e >> 4, r = e & 15;
        float f = Wpos[dsel[e] * 16 + p] + bpos[p];
        unsigned short h, l;
        split_hi_lo(f, h, l);
        int fr = mt * PM_FRAGS + (p >> 3) * 16 + r;     // kt = 0
        fS[fr * 8 + (p & 7)]                     = h;
        fS[(fr + 3 * PM_FRAGS) * 8 + (p & 7)]    = l;
    }
    for (int idx = tid; idx < 48 * 16; idx += 512) {
        int e = idx >> 4, pr = idx & 15;
        if (pr < 13) {
            int mt = e >> 4, r = e & 15;
            int A = pr / 5, Bv = pr % 5;
            int klocal = 16 + pr * 16;
            int kt = klocal >> 5, qa = (klocal >> 3) & 3;
            float dx = ctr[A][0] - nbat[e][Bv][0];
            float dy = ctr[A][1] - nbat[e][Bv][1];
            float dz = ctr[A][2] - nbat[e][Bv][2];
            float d  = sqrtf(dx * dx + dy * dy + dz * dz + 1e-6f);
            uint hw[8], lw[8];
            #pragma unroll
            for (int rp = 0; rp < 8; rp++) {
                float mu0 = 2.0f + 1.3333334f * (float)(2 * rp);
                float mu1 = 2.0f + 1.3333334f * (float)(2 * rp + 1);
                float t0 = (d - mu0) * 0.8f, t1 = (d - mu1) * 0.8f;
                float v0 = __expf(-t0 * t0), v1 = __expf(-t1 * t1);
                unsigned short h0, l0, h1, l1;
                split_hi_lo(v0, h0, l0); split_hi_lo(v1, h1, l1);
                hw[rp] = (uint)h0 | ((uint)h1 << 16);
                lw[rp] = (uint)l0 | ((uint)l1 << 16);
            }
            int fr = mt * PM_FRAGS + kt * KT_PAD + qa * 16 + r;
            frag[fr]      = make_uint4(hw[0], hw[1], hw[2], hw[3]);
            frag[fr + 16] = make_uint4(hw[4], hw[5], hw[6], hw[7]);
            frag[fr + 3 * PM_FRAGS]      = make_uint4(lw[0], lw[1], lw[2], lw[3]);
            frag[fr + 3 * PM_FRAGS + 16] = make_uint4(lw[4], lw[5], lw[6], lw[7]);
        }
    }
    __syncthreads();

    // ---- GEMM chunk 0 (ktg 0..6), W pipelined one kt ahead ----
    const uint4* fb = frag + lane;
    f32x4 acc0 = {0.f, 0.f, 0.f, 0.f}, acc1 = acc0, acc2 = acc0;
    #pragma unroll
    for (int kt = 0; kt < 7; kt++) {
        whn = *(const uint4*)(wB + (kt + 1) * 4096);
        wln = *(const uint4*)(wB + WFH_ELEMS + (kt + 1) * 4096);
        U16x8 wh, wl, a0h, a1h, a2h, a0l, a1l, a2l;
        wh.q  = whc; wl.q = wlc;
        a0h.q = fb[0 * PM_FRAGS + kt * KT_PAD];
        a1h.q = fb[1 * PM_FRAGS + kt * KT_PAD];
        a2h.q = fb[2 * PM_FRAGS + kt * KT_PAD];
        a0l.q = fb[3 * PM_FRAGS + kt * KT_PAD];
        a1l.q = fb[4 * PM_FRAGS + kt * KT_PAD];
        a2l.q = fb[5 * PM_FRAGS + kt * KT_PAD];
        acc0 = __builtin_amdgcn_mfma_f32_16x16x32_bf16(a0h.v, wh.v, acc0, 0, 0, 0);
        acc1 = __builtin_amdgcn_mfma_f32_16x16x32_bf16(a1h.v, wh.v, acc1, 0, 0, 0);
        acc2 = __builtin_amdgcn_mfma_f32_16x16x32_bf16(a2h.v, wh.v, acc2, 0, 0, 0);
        acc0 = __builtin_amdgcn_mfma_f32_16x16x32_bf16(a0l.v, wh.v, acc0, 0, 0, 0);
        acc1 = __builtin_amdgcn_mfma_f32_16x16x32_bf16(a1l.v, wh.v, acc1, 0, 0, 0);
        acc2 = __builtin_amdgcn_mfma_f32_16x16x32_bf16(a2l.v, wh.v, acc2, 0, 0, 0);
        acc0 = __builtin_amdgcn_mfma_f32_16x16x32_bf16(a0h.v, wl.v, acc0, 0, 0, 0);
        acc1 = __builtin_amdgcn_mfma_f32_16x16x32_bf16(a1h.v, wl.v, acc1, 0, 0, 0);
        acc2 = __builtin_amdgcn_mfma_f32_16x16x32_bf16(a2h.v, wl.v, acc2, 0, 0, 0);
        whc = whn; wlc = wln;
    }
    __syncthreads();   // done reading chunk-0 features; whc/wlc = kt7 in flight

    // ---- chunk 1: RBF pairs 13..24 (klocal 0..191) ----
    for (int idx = tid; idx < 48 * 16; idx += 512) {
        int e = idx >> 4, prl = idx & 15;
        if (prl < 12) {
            int mt = e >> 4, r = e & 15;
            int pr = 13 + prl;
            int A = pr / 5, Bv = pr % 5;
            int klocal = prl * 16;
            int kt = klocal >> 5, qa = (klocal >> 3) & 3;
            float dx = ctr[A][0] - nbat[e][Bv][0];
            float dy = ctr[A][1] - nbat[e][Bv][1];
            float dz = ctr[A][2] - nbat[e][Bv][2];
            float d  = sqrtf(dx * dx + dy * dy + dz * dz + 1e-6f);
            uint hw[8], lw[8];
            #pragma unroll
            for (int rp = 0; rp < 8; rp++) {
                float mu0 = 2.0f + 1.3333334f * (float)(2 * rp);
                float mu1 = 2.0f + 1.3333334f * (float)(2 * rp + 1);
                float t0 = (d - mu0) * 0.8f, t1 = (d - mu1) * 0.8f;
                float v0 = __expf(-t0 * t0), v1 = __expf(-t1 * t1);
                unsigned short h0, l0, h1, l1;
                split_hi_lo(v0, h0, l0); split_hi_lo(v1, h1, l1);
                hw[rp] = (uint)h0 | ((uint)h1 << 16);
                lw[rp] = (uint)l0 | ((uint)l1 << 16);
            }
            int fr = mt * PM_FRAGS + kt * KT_PAD + qa * 16 + r;
            frag[fr]      = make_uint4(hw[0], hw[1], hw[2], hw[3]);
            frag[fr + 16] = make_uint4(hw[4], hw[5], hw[6], hw[7]);
            frag[fr + 3 * PM_FRAGS]      = make_uint4(lw[0], lw[1], lw[2], lw[3]);
            frag[fr + 3 * PM_FRAGS + 16] = make_uint4(lw[4], lw[5], lw[6], lw[7]);
        }
    }
    __syncthreads();

    // ---- GEMM chunk 1 (ktg 7..12), W pipelined ----
    #pragma unroll
    for (int kt = 0; kt < 6; kt++) {
        if (kt < 5) {
            whn = *(const uint4*)(wB + (8 + kt) * 4096);
            wln = *(const uint4*)(wB + WFH_ELEMS + (8 + kt) * 4096);
        }
        U16x8 wh, wl, a0h, a1h, a2h, a0l, a1l, a2l;
        wh.q  = whc; wl.q = wlc;
        a0h.q = fb[0 * PM_FRAGS + kt * KT_PAD];
        a1h.q = fb[1 * PM_FRAGS + kt * KT_PAD];
        a2h.q = fb[2 * PM_FRAGS + kt * KT_PAD];
        a0l.q = fb[3 * PM_FRAGS + kt * KT_PAD];
        a1l.q = fb[4 * PM_FRAGS + kt * KT_PAD];
        a2l.q = fb[5 * PM_FRAGS + kt * KT_PAD];
        acc0 = __builtin_amdgcn_mfma_f32_16x16x32_bf16(a0h.v, wh.v, acc0, 0, 0, 0);
        acc1 = __builtin_amdgcn_mfma_f32_16x16x32_bf16(a1h.v, wh.v, acc1, 0, 0, 0);
        acc2 = __builtin_amdgcn_mfma_f32_16x16x32_bf16(a2h.v, wh.v, acc2, 0, 0, 0);
        acc0 = __builtin_amdgcn_mfma_f32_16x16x32_bf16(a0l.v, wh.v, acc0, 0, 0, 0);
        acc1 = __builtin_amdgcn_mfma_f32_16x16x32_bf16(a1l.v, wh.v, acc1, 0, 0, 0);
        acc2 = __builtin_amdgcn_mfma_f32_16x16x32_bf16(a2l.v, wh.v, acc2, 0, 0, 0);
        acc0 = __builtin_amdgcn_mfma_f32_16x16x32_bf16(a0h.v, wl.v, acc0, 0, 0, 0);
        acc1 = __builtin_amdgcn_mfma_f32_16x16x32_bf16(a1h.v, wl.v, acc1, 0, 0, 0);
        acc2 = __builtin_amdgcn_mfma_f32_16x16x32_bf16(a2h.v, wl.v, acc2, 0, 0, 0);
        whc = whn; wlc = wln;
    }

    // ---- LayerNorm ----
    // C/D layout: row = mt*16 + (lane>>4)*4 + r, col = 16w + (lane&15)
    {
        float vals[3][4] = {{acc0[0], acc0[1], acc0[2], acc0[3]},
                            {acc1[0], acc1[1], acc1[2], acc1[3]},
                            {acc2[0], acc2[1], acc2[2], acc2[3]}};
        #pragma unroll
        for (int mt = 0; mt < 3; mt++) {
            #pragma unroll
            for (int r = 0; r < 4; r++) {
                float sm = vals[mt][r], sq = sm * sm;
                #pragma unroll
                for (int off = 1; off < 16; off <<= 1) {
                    sm += __shfl_xor(sm, off);
                    sq += __shfl_xor(sq, off);
                }
                if ((lane & 15) == 0) {
                    int row = mt * 16 + ((lane >> 4) << 2) + r;
                    sumP[row][w] = sm;
                    sqP[row][w]  = sq;
                }
            }
        }
        __syncthreads();
        if (tid < 48) {
            float s = 0.f, q = 0.f;
            #pragma unroll
            for (int t = 0; t < 8; t++) { s += sumP[tid][t]; q += sqP[tid][t]; }
            float m = s * 0.0078125f;
            lnM[tid] = m;
            lnR[tid] = rsqrtf(q * 0.0078125f - m * m + 1e-5f);
        }
        __syncthreads();

        const int col = (w << 4) + (lane & 15);
        const float g  = gamma[col];
        const float bt = beta[col];
        float* Eo = Eout + (size_t)bi * KNN * EDGE_D;
        #pragma unroll
        for (int mt = 0; mt < 3; mt++) {
            #pragma unroll
            for (int r = 0; r < 4; r++) {
                int row = mt * 16 + ((lane >> 4) << 2) + r;
                Eo[(size_t)row * EDGE_D + col] =
                    (vals[mt][r] - lnM[row]) * lnR[row] * g + bt;
            }
        }
    }
}

extern "C" void kernel_launch(void* const* d_in, const int* in_sizes, int n_in,
                              void* d_out, int out_size, void* d_ws, size_t ws_size,
                              hipStream_t stream) {
    const float* X     = (const float*)d_in[0];
    const float* mask  = (const float*)d_in[1];
    const int*   ridx  = (const int*)d_in[2];
    const int*   chain = (const int*)d_in[3];
    const float* Wpos  = (const float*)d_in[4];
    const float* bpos  = (const float*)d_in[5];
    const float* Wedge = (const float*)d_in[6];
    const float* gamma = (const float*)d_in[7];
    const float* beta  = (const float*)d_in[8];

    float* out    = (float*)d_out;
    float* Eout   = out;
    float* eidx_f = out + (size_t)BB * LL * KNN * EDGE_D;
    int*   eidx_i = (int*)d_ws;
    unsigned short* Wf = (unsigned short*)((char*)d_ws + EIDX_BYTES);

    hipLaunchKernelGGL(prep_kernel, dim3((WFH_ELEMS + 255) / 256), dim3(256), 0, stream,
                       Wedge, Wf);
    hipLaunchKernelGGL(knn_kernel, dim3(BB * LL), dim3(256), 0, stream,
                       X, mask, eidx_i, eidx_f);
    hipLaunchKernelGGL(edge_kernel, dim3(BB * LL), dim3(512), 0, stream,
                       X, ridx, chain, Wpos, bpos, Wf, gamma, beta, eidx_i, Eout);
}

// Round 7
// 209.773 us; speedup vs baseline: 3.3496x; 1.0760x over previous
//
#include <hip/hip_runtime.h>
#include <hip/hip_bf16.h>
#include <stdint.h>

#define BB 2
#define LL 2048
#define KNN 48
#define MAXREL 32
#define EDGE_D 128
#define WFH_ELEMS 53248        // 13*8*64*8: one plane of W fragments
#define NKT 13
#define KT_PAD 65
#define MT_STRIDE (NKT * KT_PAD)       // 845 frags per mt
#define TOT_FRAGS (3 * MT_STRIDE)      // 2535 frags = 40560 B

typedef unsigned long long u64;
typedef __bf16 bf16_t;
typedef bf16_t bf16x8 __attribute__((ext_vector_type(8)));
typedef float f32x4 __attribute__((ext_vector_type(4)));

union U16x8 { uint4 q; bf16x8 v; };

__device__ __forceinline__ u64 u64min(u64 a, u64 b) { return a < b ? a : b; }

__device__ __forceinline__ u64 shfl_xor_u64(u64 v, int m) {
    unsigned lo = __shfl_xor((unsigned)(v & 0xffffffffull), m);
    unsigned hi = __shfl_xor((unsigned)(v >> 32), m);
    return (((u64)hi) << 32) | lo;
}

// truncation split (W prep): f = hi + lo + eps, |eps| ~ 2^-16 |f|
__device__ __forceinline__ void split_hi_lo(float f, unsigned short& h, unsigned short& l) {
    unsigned bits = __float_as_uint(f);
    h = (unsigned short)(bits >> 16);
    float hf = __uint_as_float(bits & 0xffff0000u);
    float lo = f - hf;
    l = (unsigned short)(__float_as_uint(lo) >> 16);
}

// round-to-nearest-even bf16 (A features; no NaN inputs here)
__device__ __forceinline__ unsigned bf16rn(float f) {
    unsigned u = __float_as_uint(f);
    return (u + 0x7fffu + ((u >> 16) & 1u)) >> 16;
}

// ---------------------------------------------------------------------------
// Kernel 0: split W_edge (416x128 f32) into bf16 hi/lo planes, pre-swizzled
// into mfma_f32_16x16x32_bf16 B-fragment order.
// ---------------------------------------------------------------------------
__global__ __launch_bounds__(256) void prep_kernel(const float* __restrict__ W,
                                                   unsigned short* __restrict__ Wf)
{
    int tid = blockIdx.x * 256 + threadIdx.x;
    if (tid >= WFH_ELEMS) return;
    int e    = tid & 7;
    int lane = (tid >> 3) & 63;
    int nt   = (tid >> 9) & 7;
    int ktg  = tid >> 12;
    int k    = ktg * 32 + ((lane >> 4) << 3) + e;
    int col  = (nt << 4) + (lane & 15);
    float f  = W[k * 128 + col];
    unsigned short h, l;
    split_hi_lo(f, h, l);
    Wf[tid]             = h;
    Wf[tid + WFH_ELEMS] = l;
}

// ---------------------------------------------------------------------------
// Fused kernel: per (b,i) WG of 512 threads:
//   Phase K: exact kNN (linear-value histogram rank-48 + 64-key bitonic sort;
//            u64 key = dadj_bits<<32|j == jax.lax.top_k order; extract-min
//            fallback for degenerate ties). Selected indices stay in LDS.
//   Phase F: features (positional gather + 25x16 RBF), A in single rtn-bf16
//            plane, written directly in MFMA A-fragment order.
//   Phase G: 48x416 @ 416x128 GEMM, 13 kts x (3 A-frags x {Wh,Wl}) MFMAs,
//            W streamed from L2 with 1-deep pipeline.
//   Phase L: LayerNorm + store.
// ---------------------------------------------------------------------------
__global__ __launch_bounds__(512, 6) void fused_kernel(
    const float* __restrict__ X, const float* __restrict__ mask,
    const int*   __restrict__ ridx, const int* __restrict__ chain,
    const float* __restrict__ Wpos, const float* __restrict__ bpos,
    const unsigned short* __restrict__ Wf,
    const float* __restrict__ gamma, const float* __restrict__ beta,
    float* __restrict__ Eout, float* __restrict__ eidx_f)
{
    __shared__ __align__(16) uint4 frag[TOT_FRAGS];
    __shared__ float nbat[48][5][3];
    __shared__ float ctr[5][3];
    __shared__ int   dsel[48];
    __shared__ int   selj[48];
    __shared__ float sumP[48][8];
    __shared__ float sqP[48][8];
    __shared__ float lnM[48], lnR[48];
    // knn scratch
    __shared__ int   hist[256];
    __shared__ int   ctrl[4];
    __shared__ int   cnt;
    __shared__ u64   list[64];
    __shared__ float wshA[8], wshB[8];
    __shared__ u64   wmin[2][8];

    const int bi   = blockIdx.x;
    const int b    = bi >> 11;
    const int i    = bi & (LL - 1);
    const int tid  = threadIdx.x;
    const int w    = tid >> 6;
    const int lane = tid & 63;
    const float* Xb = X + (size_t)b * LL * 12;
    const float* mb = mask + (size_t)b * LL;

    // W pipeline prologue: kt=0 fragments load during the whole knn phase
    const unsigned short* wB = Wf + (size_t)w * 512 + (size_t)lane * 8;
    uint4 whc = *(const uint4*)(wB);
    uint4 wlc = *(const uint4*)(wB + WFH_ELEMS);
    uint4 whn, wln;

    // ================= Phase K: kNN =================
    const float cax = Xb[i * 12 + 3];
    const float cay = Xb[i * 12 + 4];
    const float caz = Xb[i * 12 + 5];
    const float mi  = mb[i];

    float D[4], M2[4];
    float dmax = 0.0f;
    #pragma unroll
    for (int t = 0; t < 4; t++) {
        int j = (t << 9) + tid;
        float dx = Xb[j * 12 + 3] - cax;
        float dy = Xb[j * 12 + 4] - cay;
        float dz = Xb[j * 12 + 5] - caz;
        float s  = __fadd_rn(__fadd_rn(__fmul_rn(dx, dx), __fmul_rn(dy, dy)),
                             __fmul_rn(dz, dz));
        float m2 = __fmul_rn(mi, mb[j]);
        float d  = __fmul_rn(m2, sqrtf(__fadd_rn(s, 1e-6f)));
        D[t]  = d;
        M2[t] = m2;
        dmax  = fmaxf(dmax, d);
    }

    if (tid < 256) hist[tid] = 0;
    if (tid == 0) cnt = 0;

    #pragma unroll
    for (int off = 32; off; off >>= 1) dmax = fmaxf(dmax, __shfl_xor(dmax, off));
    if (lane == 0) wshA[w] = dmax;
    __syncthreads();
    dmax = wshA[0];
    #pragma unroll
    for (int t = 1; t < 8; t++) dmax = fmaxf(dmax, wshA[t]);

    u64 key[4];
    float dadj[4];
    float dmin = 3.4e38f;
    #pragma unroll
    for (int t = 0; t < 4; t++) {
        int j = (t << 9) + tid;
        float da = __fadd_rn(D[t], __fmul_rn(1.0f - M2[t], dmax));
        dadj[t] = da;
        key[t] = (((u64)__float_as_uint(da)) << 32) | (unsigned)j;
        dmin = fminf(dmin, da);
    }
    #pragma unroll
    for (int off = 32; off; off >>= 1) dmin = fminf(dmin, __shfl_xor(dmin, off));
    if (lane == 0) wshB[w] = dmin;
    __syncthreads();
    dmin = wshB[0];
    #pragma unroll
    for (int t = 1; t < 8; t++) dmin = fminf(dmin, wshB[t]);

    const float range = dmax - dmin;
    const float scale = (range > 1e-35f) ? (255.0f / range) : 0.0f;

    int bin[4];
    #pragma unroll
    for (int t = 0; t < 4; t++) {
        int bb = (int)((dadj[t] - dmin) * scale);
        bin[t] = bb > 255 ? 255 : bb;
        atomicAdd(&hist[bin[t]], 1);
    }
    __syncthreads();

    if (w == 0) {        // scan 1
        int h0 = hist[4 * lane], h1 = hist[4 * lane + 1];
        int h2 = hist[4 * lane + 2], h3 = hist[4 * lane + 3];
        int s = h0 + h1 + h2 + h3;
        int sc = s;
        #pragma unroll
        for (int off = 1; off < 64; off <<= 1) {
            int o = __shfl_up(sc, off);
            if (lane >= off) sc += o;
        }
        u64 ball = __ballot(sc >= KNN);
        int fl = __ffsll((unsigned long long)ball) - 1;
        if (lane == fl) {
            int cb = sc - s;
            int B, cbB, m1;
            if      (cb + h0 >= KNN)           { B = 4*lane;   cbB = cb;          m1 = cb+h0; }
            else if (cb + h0 + h1 >= KNN)      { B = 4*lane+1; cbB = cb+h0;       m1 = cb+h0+h1; }
            else if (cb + h0 + h1 + h2 >= KNN) { B = 4*lane+2; cbB = cb+h0+h1;    m1 = cb+h0+h1+h2; }
            else                               { B = 4*lane+3; cbB = cb+h0+h1+h2; m1 = cb+h0+h1+h2+h3; }
            ctrl[0] = B; ctrl[1] = cbB; ctrl[2] = m1;
        }
    }
    __syncthreads();
    const int B = ctrl[0], cbB = ctrl[1], m1 = ctrl[2];

    if (m1 <= 64) {
        #pragma unroll
        for (int t = 0; t < 4; t++)
            if (bin[t] <= B) { int p = atomicAdd(&cnt, 1); list[p] = key[t]; }
        __syncthreads();
        if (w == 0) {
            u64 v = (lane < m1) ? list[lane] : ~0ull;
            #pragma unroll
            for (int k = 2; k <= 64; k <<= 1)
                #pragma unroll
                for (int j = k >> 1; j > 0; j >>= 1) {
                    u64 o = shfl_xor_u64(v, j);
                    bool takemin = (((lane & k) == 0) == ((lane & j) == 0));
                    u64 mn = u64min(v, o);
                    u64 mx = v ^ o ^ mn;
                    v = takemin ? mn : mx;
                }
            if (lane < KNN) {
                int j = (int)(v & 0xffffffffu);
                selj[lane] = j;
                eidx_f[(size_t)bi * KNN + lane] = (float)j;
            }
        }
    } else {
        // pass 2: refine within bin B
        if (tid < 256) hist[tid] = 0;
        __syncthreads();
        const float width  = range * (1.0f / 255.0f);
        const float b_lo   = dmin + (float)B * width;
        const float scale2 = (width > 1e-35f) ? (255.0f / width) : 0.0f;
        int bin2[4];
        #pragma unroll
        for (int t = 0; t < 4; t++) {
            if (bin[t] == B) {
                int bb = (int)((dadj[t] - b_lo) * scale2);
                bb = bb < 0 ? 0 : (bb > 255 ? 255 : bb);
                bin2[t] = bb;
                atomicAdd(&hist[bb], 1);
            } else bin2[t] = 1 << 30;
        }
        __syncthreads();
        if (w == 0) {
            const int T2 = KNN - cbB;
            int h0 = hist[4 * lane], h1 = hist[4 * lane + 1];
            int h2 = hist[4 * lane + 2], h3 = hist[4 * lane + 3];
            int s = h0 + h1 + h2 + h3;
            int sc = s;
            #pragma unroll
            for (int off = 1; off < 64; off <<= 1) {
                int o = __shfl_up(sc, off);
                if (lane >= off) sc += o;
            }
            u64 ball = __ballot(sc >= T2);
            int fl = __ffsll((unsigned long long)ball) - 1;
            if (lane == fl) {
                int cb = sc - s;
                int B2, cum;
                if      (cb + h0 >= T2)           { B2 = 4*lane;   cum = cb+h0; }
                else if (cb + h0 + h1 >= T2)      { B2 = 4*lane+1; cum = cb+h0+h1; }
                else if (cb + h0 + h1 + h2 >= T2) { B2 = 4*lane+2; cum = cb+h0+h1+h2; }
                else                              { B2 = 4*lane+3; cum = cb+h0+h1+h2+h3; }
                ctrl[2] = B2; ctrl[3] = cbB + cum;
            }
        }
        __syncthreads();
        const int B2 = ctrl[2], m2 = ctrl[3];

        if (m2 <= 64) {
            #pragma unroll
            for (int t = 0; t < 4; t++)
                if (bin[t] < B || (bin[t] == B && bin2[t] <= B2)) {
                    int p = atomicAdd(&cnt, 1); list[p] = key[t];
                }
            __syncthreads();
            if (w == 0) {
                u64 v = (lane < m2) ? list[lane] : ~0ull;
                #pragma unroll
                for (int k = 2; k <= 64; k <<= 1)
                    #pragma unroll
                    for (int j = k >> 1; j > 0; j >>= 1) {
                        u64 o = shfl_xor_u64(v, j);
                        bool takemin = (((lane & k) == 0) == ((lane & j) == 0));
                        u64 mn = u64min(v, o);
                        u64 mx = v ^ o ^ mn;
                        v = takemin ? mn : mx;
                    }
                if (lane < KNN) {
                    int j = (int)(v & 0xffffffffu);
                    selj[lane] = j;
                    eidx_f[(size_t)bi * KNN + lane] = (float)j;
                }
            }
        } else {
            // degenerate ties: exact extract-min fallback
            for (int s = 0; s < KNN; s++) {
                u64 lmin = key[0];
                #pragma unroll
                for (int t = 1; t < 4; t++) lmin = u64min(lmin, key[t]);
                #pragma unroll
                for (int off = 1; off < 64; off <<= 1) lmin = u64min(lmin, shfl_xor_u64(lmin, off));
                if (lane == 0) wmin[s & 1][w] = lmin;
                __syncthreads();
                u64 gmin = wmin[s & 1][0];
                #pragma unroll
                for (int t = 1; t < 8; t++) gmin = u64min(gmin, wmin[s & 1][t]);
                if (tid == 0) {
                    int j = (int)(gmin & 0xffffffffu);
                    selj[s] = j;
                    eidx_f[(size_t)bi * KNN + s] = (float)j;
                }
                #pragma unroll
                for (int t = 0; t < 4; t++) if (key[t] == gmin) key[t] = ~0ull;
            }
        }
    }
    __syncthreads();   // selj complete

    // ================= Phase F: meta + atoms + features =================
    if (tid < 48) {
        int j = selj[tid];
        int off = ridx[b * LL + i] - ridx[b * LL + j];
        int sc  = (chain[b * LL + i] == chain[b * LL + j]);
        int d   = off + MAXREL;
        d = d < 0 ? 0 : (d > 2 * MAXREL ? 2 * MAXREL : d);
        dsel[tid] = sc ? d : (2 * MAXREL + 1);
    }
    if (tid >= 448 && tid < 452) {
        int a = tid - 448;                       // 0=Ca,1=N,2=C,3=O
        int src = (a == 0) ? 1 : ((a == 1) ? 0 : a);
        ctr[a][0] = Xb[i * 12 + src * 3 + 0];
        ctr[a][1] = Xb[i * 12 + src * 3 + 1];
        ctr[a][2] = Xb[i * 12 + src * 3 + 2];
    }
    if (tid < 192) {
        int e = tid >> 2, a = tid & 3;
        int src = (a == 0) ? 1 : ((a == 1) ? 0 : a);
        int j = selj[e];
        nbat[e][a][0] = Xb[j * 12 + src * 3 + 0];
        nbat[e][a][1] = Xb[j * 12 + src * 3 + 1];
        nbat[e][a][2] = Xb[j * 12 + src * 3 + 2];
    }
    __syncthreads();

    // virtual Cb
    if (tid < 48) {
        float bx = nbat[tid][0][0] - nbat[tid][1][0];
        float by = nbat[tid][0][1] - nbat[tid][1][1];
        float bz = nbat[tid][0][2] - nbat[tid][1][2];
        float cx = nbat[tid][2][0] - nbat[tid][0][0];
        float cy = nbat[tid][2][1] - nbat[tid][0][1];
        float cz = nbat[tid][2][2] - nbat[tid][0][2];
        float ax = by * cz - bz * cy;
        float ay = bz * cx - bx * cz;
        float az = bx * cy - by * cx;
        nbat[tid][4][0] = -0.58273431f * ax + 0.56802827f * bx - 0.54067466f * cx + nbat[tid][0][0];
        nbat[tid][4][1] = -0.58273431f * ay + 0.56802827f * by - 0.54067466f * cy + nbat[tid][0][1];
        nbat[tid][4][2] = -0.58273431f * az + 0.56802827f * bz - 0.54067466f * cz + nbat[tid][0][2];
    } else if (tid == 48) {
        float bx = ctr[0][0] - ctr[1][0];
        float by = ctr[0][1] - ctr[1][1];
        float bz = ctr[0][2] - ctr[1][2];
        float cx = ctr[2][0] - ctr[0][0];
        float cy = ctr[2][1] - ctr[0][1];
        float cz = ctr[2][2] - ctr[0][2];
        float ax = by * cz - bz * cy;
        float ay = bz * cx - bx * cz;
        float az = bx * cy - by * cx;
        ctr[4][0] = -0.58273431f * ax + 0.56802827f * bx - 0.54067466f * cx + ctr[0][0];
        ctr[4][1] = -0.58273431f * ay + 0.56802827f * by - 0.54067466f * cy + ctr[0][1];
        ctr[4][2] = -0.58273431f * az + 0.56802827f * bz - 0.54067466f * cz + ctr[0][2];
    }
    __syncthreads();

    unsigned short* fS = (unsigned short*)frag;   // scalar view

    // positional: k 0..15 (kt 0, qa 0..1), single bf16 plane
    for (int idx = tid; idx < 48 * 16; idx += 512) {
        int e = idx >> 4, p = idx & 15;
        int mt = e >> 4, r = e & 15;
        float f = Wpos[dsel[e] * 16 + p] + bpos[p];
        int fr = mt * MT_STRIDE + (p >> 3) * 16 + r;     // kt = 0
        fS[fr * 8 + (p & 7)] = (unsigned short)bf16rn(f);
    }
    // RBF: pair pr covers k 16+16pr .. 31+16pr  (pr 0..24)
    for (int idx = tid; idx < 48 * 25; idx += 512) {
        int e = idx / 25, pr = idx % 25;
        int mt = e >> 4, r = e & 15;
        int A = pr / 5, Bv = pr % 5;
        int klocal = 16 + pr * 16;
        int kt = klocal >> 5, qa = (klocal >> 3) & 3;
        float dx = ctr[A][0] - nbat[e][Bv][0];
        float dy = ctr[A][1] - nbat[e][Bv][1];
        float dz = ctr[A][2] - nbat[e][Bv][2];
        float d  = sqrtf(dx * dx + dy * dy + dz * dz + 1e-6f);
        uint hw[8];
        #pragma unroll
        for (int rp = 0; rp < 8; rp++) {
            float mu0 = 2.0f + 1.3333334f * (float)(2 * rp);
            float mu1 = 2.0f + 1.3333334f * (float)(2 * rp + 1);
            float t0 = (d - mu0) * 0.8f, t1 = (d - mu1) * 0.8f;
            float v0 = __expf(-t0 * t0), v1 = __expf(-t1 * t1);
            hw[rp] = bf16rn(v0) | (bf16rn(v1) << 16);
        }
        int fr = mt * MT_STRIDE + kt * KT_PAD + qa * 16 + r;
        frag[fr]      = make_uint4(hw[0], hw[1], hw[2], hw[3]);
        frag[fr + 16] = make_uint4(hw[4], hw[5], hw[6], hw[7]);
    }
    __syncthreads();

    // ================= Phase G: GEMM (13 kts, W pipelined) =================
    const uint4* fb = frag + lane;
    f32x4 acc0 = {0.f, 0.f, 0.f, 0.f}, acc1 = acc0, acc2 = acc0;
    #pragma unroll
    for (int kt = 0; kt < NKT; kt++) {
        if (kt < NKT - 1) {
            whn = *(const uint4*)(wB + (kt + 1) * 4096);
            wln = *(const uint4*)(wB + WFH_ELEMS + (kt + 1) * 4096);
        }
        U16x8 wh, wl, a0, a1, a2;
        wh.q = whc; wl.q = wlc;
        a0.q = fb[0 * MT_STRIDE + kt * KT_PAD];
        a1.q = fb[1 * MT_STRIDE + kt * KT_PAD];
        a2.q = fb[2 * MT_STRIDE + kt * KT_PAD];
        acc0 = __builtin_amdgcn_mfma_f32_16x16x32_bf16(a0.v, wh.v, acc0, 0, 0, 0);
        acc1 = __builtin_amdgcn_mfma_f32_16x16x32_bf16(a1.v, wh.v, acc1, 0, 0, 0);
        acc2 = __builtin_amdgcn_mfma_f32_16x16x32_bf16(a2.v, wh.v, acc2, 0, 0, 0);
        acc0 = __builtin_amdgcn_mfma_f32_16x16x32_bf16(a0.v, wl.v, acc0, 0, 0, 0);
        acc1 = __builtin_amdgcn_mfma_f32_16x16x32_bf16(a1.v, wl.v, acc1, 0, 0, 0);
        acc2 = __builtin_amdgcn_mfma_f32_16x16x32_bf16(a2.v, wl.v, acc2, 0, 0, 0);
        whc = whn; wlc = wln;
    }

    // ================= Phase L: LayerNorm + store =================
    // C/D layout: row = mt*16 + (lane>>4)*4 + r, col = 16w + (lane&15)
    {
        float vals[3][4] = {{acc0[0], acc0[1], acc0[2], acc0[3]},
                            {acc1[0], acc1[1], acc1[2], acc1[3]},
                            {acc2[0], acc2[1], acc2[2], acc2[3]}};
        #pragma unroll
        for (int mt = 0; mt < 3; mt++) {
            #pragma unroll
            for (int r = 0; r < 4; r++) {
                float sm = vals[mt][r], sq = sm * sm;
                #pragma unroll
                for (int off = 1; off < 16; off <<= 1) {
                    sm += __shfl_xor(sm, off);
                    sq += __shfl_xor(sq, off);
                }
                if ((lane & 15) == 0) {
                    int row = mt * 16 + ((lane >> 4) << 2) + r;
                    sumP[row][w] = sm;
                    sqP[row][w]  = sq;
                }
            }
        }
        __syncthreads();
        if (tid < 48) {
            float s = 0.f, q = 0.f;
            #pragma unroll
            for (int t = 0; t < 8; t++) { s += sumP[tid][t]; q += sqP[tid][t]; }
            float m = s * 0.0078125f;
            lnM[tid] = m;
            lnR[tid] = rsqrtf(q * 0.0078125f - m * m + 1e-5f);
        }
        __syncthreads();

        const int col = (w << 4) + (lane & 15);
        const float g  = gamma[col];
        const float bt = beta[col];
        float* Eo = Eout + (size_t)bi * KNN * EDGE_D;
        #pragma unroll
        for (int mt = 0; mt < 3; mt++) {
            #pragma unroll
            for (int r = 0; r < 4; r++) {
                int row = mt * 16 + ((lane >> 4) << 2) + r;
                Eo[(size_t)row * EDGE_D + col] =
                    (vals[mt][r] - lnM[row]) * lnR[row] * g + bt;
            }
        }
    }
}

extern "C" void kernel_launch(void* const* d_in, const int* in_sizes, int n_in,
                              void* d_out, int out_size, void* d_ws, size_t ws_size,
                              hipStream_t stream) {
    const float* X     = (const float*)d_in[0];
    const float* mask  = (const float*)d_in[1];
    const int*   ridx  = (const int*)d_in[2];
    const int*   chain = (const int*)d_in[3];
    const float* Wpos  = (const float*)d_in[4];
    const float* bpos  = (const float*)d_in[5];
    const float* Wedge = (const float*)d_in[6];
    const float* gamma = (const float*)d_in[7];
    const float* beta  = (const float*)d_in[8];

    float* out    = (float*)d_out;
    float* Eout   = out;
    float* eidx_f = out + (size_t)BB * LL * KNN * EDGE_D;
    unsigned short* Wf = (unsigned short*)d_ws;

    hipLaunchKernelGGL(prep_kernel, dim3((WFH_ELEMS + 255) / 256), dim3(256), 0, stream,
                       Wedge, Wf);
    hipLaunchKernelGGL(fused_kernel, dim3(BB * LL), dim3(512), 0, stream,
                       X, mask, ridx, chain, Wpos, bpos, Wf, gamma, beta,
                       Eout, eidx_f);
}